// Round 22
// baseline (277.990 us; speedup 1.0000x reference)
//
#include <hip/hip_runtime.h>
#include <hip/hip_bf16.h>
#include <math.h>

#define C     768
#define HEADS 12
#define HD    64
#define NF    8
#define SL    196
#define BB    2
#define NN    1569   // 1 + NF*SL
#define SS    1568   // NF*SL
#define HID   3072
#define CLS_CH 256
#define CLS_NC 7     // ceil(NN / CLS_CH)
#define QSCALE 0.18033688011112042f   // 0.125 * log2(e); scores live in log2 domain

typedef __attribute__((ext_vector_type(8))) short short8;
typedef __attribute__((ext_vector_type(4))) float f32x4;
typedef unsigned short u16;
typedef unsigned int u32;

__device__ inline float fast_exp2(float x) { return __builtin_amdgcn_exp2f(x); }

__device__ inline u16 f2b(float f) {
    __hip_bfloat16 h = __float2bfloat16(f);   // HW v_cvt path (RNE)
    return *reinterpret_cast<u16*>(&h);
}
__device__ inline float b2f(u16 u) {
    union { unsigned u; float f; } v; v.u = ((unsigned)u) << 16;
    return v.f;
}

__device__ inline void gload_lds16(const void* g, void* l) {
    __builtin_amdgcn_global_load_lds(
        (const __attribute__((address_space(1))) void*)g,
        (__attribute__((address_space(3))) void*)l, 16, 0, 0);
}

// ---------------- LayerNorm: f32 in -> bf16 out ----------------
__global__ void ln_kernel(const float* __restrict__ x, const float* __restrict__ g,
                          const float* __restrict__ b, u16* __restrict__ out, int rows) {
    int row = blockIdx.x;
    if (row >= rows) return;
    const float* xr = x + (size_t)row * C;
    int tid = threadIdx.x;
    float v[3];
    float sum = 0.f, sumsq = 0.f;
#pragma unroll
    for (int i = 0; i < 3; i++) {
        v[i] = xr[tid + 256 * i];
        sum += v[i]; sumsq += v[i] * v[i];
    }
    __shared__ float s1[4], s2[4];
    for (int off = 32; off; off >>= 1) {
        sum   += __shfl_xor(sum, off);
        sumsq += __shfl_xor(sumsq, off);
    }
    int wave = tid >> 6, lane = tid & 63;
    if (lane == 0) { s1[wave] = sum; s2[wave] = sumsq; }
    __syncthreads();
    sum   = s1[0] + s1[1] + s1[2] + s1[3];
    sumsq = s2[0] + s2[1] + s2[2] + s2[3];
    float mu  = sum / C;
    float var = sumsq / C - mu * mu;
    float rstd = rsqrtf(fmaxf(var, 0.f) + 1e-5f);
    u16* outr = out + (size_t)row * C;
#pragma unroll
    for (int i = 0; i < 3; i++) {
        int c = tid + 256 * i;
        outr[c] = f2b((v[i] - mu) * rstd * g[c] + b[c]);
    }
}

// ---------------- fused weight transpose+convert (all 6 weights, one launch) ----------------
__global__ void wtrans_all_kernel(
    const float* __restrict__ Wqkv, const float* __restrict__ Wq,
    const float* __restrict__ Wkv,  const float* __restrict__ Wp,
    const float* __restrict__ W1,   const float* __restrict__ W2,
    u16* Tqkv, u16* Tq, u16* Tkv, u16* Tp, u16* T1, u16* T2) {
    __shared__ float tile[64][65];
    int bid = blockIdx.x;
    const float* W; u16* Wt; int K, ldb, gx;
    if (bid < 432)       { W = Wqkv; Wt = Tqkv; K = 768;  ldb = 2304; gx = 36; }
    else if (bid < 576)  { W = Wq;   Wt = Tq;   K = 768;  ldb = 768;  gx = 12; bid -= 432; }
    else if (bid < 720)  { W = Wkv;  Wt = Tkv;  K = 768;  ldb = 1536; gx = 12; bid -= 576; }
    else if (bid < 864)  { W = Wp;   Wt = Tp;   K = 768;  ldb = 768;  gx = 12; bid -= 720; }
    else if (bid < 1440) { W = W1;   Wt = T1;   K = 768;  ldb = 3072; gx = 48; bid -= 864; }
    else                 { W = W2;   Wt = T2;   K = 3072; ldb = 768;  gx = 12; bid -= 1440; }
    int nb = (bid % gx) * 64, kb = (bid / gx) * 64;
    int tx = threadIdx.x & 63, ty = threadIdx.x >> 6;
#pragma unroll
    for (int i = 0; i < 64; i += 4)
        tile[ty + i][tx] = W[(size_t)(kb + ty + i) * ldb + nb + tx];
    __syncthreads();
#pragma unroll
    for (int i = 0; i < 64; i += 4)
        Wt[(size_t)(nb + ty + i) * K + kb + tx] = f2b(tile[tx][ty + i]);
}

// ---------------- bf16 MFMA GEMM (2-phase dbuf, XCD-swizzled 1-D grid) ----------------
// Tiled BM x BN with WAVES waves (2 rows x WAVES/2 cols); wave tile (BM/2) x (BN/(WAVES/2)).
// MODE 0: bf16 out. MODE 1: bf16 out, bias + exact GELU. MODE 2: f32 out, bias + resid.
// MODE 3: bf16 out, cols < 768 scaled by QSCALE. MODE 4: split-K f32 partials.
template<int MODE, int BM, int BN, int WAVES>
__global__ __launch_bounds__(WAVES * 64) void gemm_bf16(
    const u16* __restrict__ A, const u16* __restrict__ Bt,
    const float* __restrict__ bias, const float* resid, void* Cout,
    int M, int N, int K, int lda, int ldb, int gx) {
    constexpr int WCOLS = WAVES / 2;
    constexpr int WBN   = BN / WCOLS;
    constexpr int MT    = BM / 32;
    constexpr int NT    = WBN / 16;
    constexpr int ACH   = BM * 4;
    constexpr int TCH   = (BM + BN) * 4;
    constexpr int HALF  = (BM + BN) * 64;
    __shared__ char smem[2 * HALF];
    int tid = threadIdx.x, lane = tid & 63, wave = tid >> 6;
    int wr = wave / WCOLS, wc = wave % WCOLS;
    int r16 = lane & 15, kg = lane >> 4;

    int nwg = gridDim.x, orig = blockIdx.x;
    int qq = nwg >> 3, rr = nwg & 7, xcd = orig & 7, lid = orig >> 3;
    int wg = (xcd < rr ? xcd * (qq + 1) : rr * (qq + 1) + (xcd - rr) * qq) + lid;
    int bx = wg % gx, by = wg / gx;
    if constexpr (MODE == 4) {
        int mt_ = (M + BM - 1) / BM;
        int chunk = by / mt_; by -= chunk * mt_;
        A    += (size_t)chunk * K;
        Bt   += (size_t)chunk * K;
        Cout  = (void*)((float*)Cout + (size_t)chunk * ((size_t)M * N));
    }
    int row0 = by * BM, col0 = bx * BN;

    f32x4 acc[MT][NT];
#pragma unroll
    for (int mt = 0; mt < MT; mt++)
#pragma unroll
        for (int nt = 0; nt < NT; nt++) acc[mt][nt] = (f32x4){0.f, 0.f, 0.f, 0.f};

    auto stage = [&](char* dstbase, int ks) {
        int k0 = ks << 5;
#pragma unroll
        for (int it = 0; it < TCH / (WAVES * 64); it++) {
            int c = it * (WAVES * 64) + tid;
            const u16* src;
            if (c < ACH) {
                int ml = c >> 2, s = c & 3;
                int kgs = s ^ ((ml >> 1) & 3);
                int gm = row0 + ml; if (gm >= M) gm = M - 1;
                src = A + (size_t)gm * lda + k0 + kgs * 8;
            } else {
                int cc = c - ACH;
                int nl = cc >> 2, s = cc & 3;
                int kgs = s ^ ((nl >> 1) & 3);
                src = Bt + (size_t)(col0 + nl) * ldb + k0 + kgs * 8;
            }
            gload_lds16(src, dstbase + it * (WAVES * 1024) + wave * 1024);
        }
    };

    int nsteps = K >> 5;
    stage(smem, 0);
    __syncthreads();
    for (int ks = 0; ks < nsteps; ks++) {
        char* curb = smem + (ks & 1) * HALF;
        if (ks + 1 < nsteps) stage(smem + ((ks + 1) & 1) * HALF, ks + 1);
        short8 af[MT], bfr[NT];
#pragma unroll
        for (int mt = 0; mt < MT; mt++) {
            int ml = wr * (BM / 2) + mt * 16 + r16;
            af[mt] = *(const short8*)(curb + ml * 64 + ((kg ^ ((ml >> 1) & 3)) << 4));
        }
#pragma unroll
        for (int nt = 0; nt < NT; nt++) {
            int nl = wc * WBN + nt * 16 + r16;
            bfr[nt] = *(const short8*)(curb + BM * 64 + nl * 64 + ((kg ^ ((nl >> 1) & 3)) << 4));
        }
        __builtin_amdgcn_s_setprio(1);
#pragma unroll
        for (int mt = 0; mt < MT; mt++)
#pragma unroll
            for (int nt = 0; nt < NT; nt++)
                acc[mt][nt] = __builtin_amdgcn_mfma_f32_16x16x32_bf16(af[mt], bfr[nt], acc[mt][nt], 0, 0, 0);
        __builtin_amdgcn_s_setprio(0);
        __syncthreads();
    }
#pragma unroll
    for (int mt = 0; mt < MT; mt++) {
#pragma unroll
        for (int r2 = 0; r2 < 4; r2++) {
            int gm = row0 + wr * (BM / 2) + mt * 16 + kg * 4 + r2;
            if (gm >= M) continue;
#pragma unroll
            for (int nt = 0; nt < NT; nt++) {
                int gn = col0 + wc * WBN + nt * 16 + r16;
                float v = acc[mt][nt][r2];
                if constexpr (MODE == 1) {
                    v += bias[gn];
                    v = 0.5f * v * (1.f + erff(v * 0.70710678118f));
                }
                if constexpr (MODE == 2) {
                    v += bias[gn] + resid[(size_t)gm * N + gn];
                    ((float*)Cout)[(size_t)gm * N + gn] = v;
                } else if constexpr (MODE == 4) {
                    ((float*)Cout)[(size_t)gm * N + gn] = v;
                } else {
                    if constexpr (MODE == 3) { if (gn < 768) v *= QSCALE; }
                    ((u16*)Cout)[(size_t)gm * N + gn] = f2b(v);
                }
            }
        }
    }
}

// ---------------- fc2 split-K=2 merge: out += p0+p1 + bias (float4) ----------------
__global__ void fc2_merge_kernel(const float* __restrict__ p,
                                 const float* __restrict__ bias, float* __restrict__ out) {
    int i = blockIdx.x * 256 + threadIdx.x;
    int total = BB * NN * (C / 4);
    if (i >= total) return;
    int c4 = i % (C / 4);
    size_t stride = (size_t)BB * NN * (C / 4);
    float4 bb = ((const float4*)bias)[c4];
    float4 a0 = ((const float4*)p)[i];
    float4 a1 = ((const float4*)p)[i + stride];
    float4 o  = ((float4*)out)[i];
    o.x += a0.x + a1.x + bb.x;
    o.y += a0.y + a1.y + bb.y;
    o.z += a0.z + a1.z + bb.z;
    o.w += a0.w + a1.w + bb.w;
    ((float4*)out)[i] = o;
}

// ---------------- cls attention pass 1 (q pre-scaled; log2-domain softmax) ----------------
__global__ void cls_partial_kernel(const u16* __restrict__ qkv, float* __restrict__ part) {
    int c = blockIdx.x, bh = blockIdx.y;
    int b = bh / HEADS, hh = bh % HEADS;
    int tid = threadIdx.x;
    int wave = tid >> 6, lane = tid & 63;
    __shared__ float s_q[HD];
    __shared__ float s_sc[CLS_CH];
    __shared__ float sm[4], ss[4];
    __shared__ float sacc[4][HD];
    if (tid < HD) s_q[tid] = b2f(qkv[(size_t)(b * NN) * 2304 + hh * HD + tid]);
    __syncthreads();

    int j0 = c * CLS_CH;
    int j = j0 + tid;
    float sc = -1e30f;
    if (j < NN) {
        const short8* kp = (const short8*)(qkv + ((size_t)(b * NN) + j) * 2304 + C + hh * HD);
        float acc = 0.f;
#pragma unroll
        for (int u = 0; u < 8; u++) {
            short8 kv = kp[u];
#pragma unroll
            for (int e = 0; e < 8; e++) acc += s_q[u * 8 + e] * b2f((u16)kv[e]);
        }
        sc = acc;
    }
    float m = sc;
    for (int off = 32; off; off >>= 1) m = fmaxf(m, __shfl_xor(m, off));
    if (lane == 0) sm[wave] = m;
    __syncthreads();
    m = fmaxf(fmaxf(sm[0], sm[1]), fmaxf(sm[2], sm[3]));
    float e = (j < NN) ? fast_exp2(sc - m) : 0.f;
    s_sc[tid] = e;
    float su = e;
    for (int off = 32; off; off >>= 1) su += __shfl_xor(su, off);
    if (lane == 0) ss[wave] = su;
    __syncthreads();
    float ssum = ss[0] + ss[1] + ss[2] + ss[3];

    int jj = tid >> 6, d = tid & 63;
    int jmax = NN - j0; if (jmax > CLS_CH) jmax = CLS_CH;
    const u16* vcol = qkv + ((size_t)(b * NN) + j0) * 2304 + 2 * C + hh * HD + d;
    float acc = 0.f;
    for (int t = jj; t < jmax; t += 4)
        acc += s_sc[t] * b2f(vcol[(size_t)t * 2304]);
    sacc[jj][d] = acc;
    __syncthreads();
    if (tid < HD) {
        float pv = sacc[0][tid] + sacc[1][tid] + sacc[2][tid] + sacc[3][tid];
        float* pp = part + ((size_t)bh * CLS_NC + c) * 66;
        pp[2 + tid] = pv;
        if (tid == 0) { pp[0] = m; pp[1] = ssum; }
    }
}

// ---------------- cls attention pass 2: merge chunk partials (log2 domain) ----------------
__global__ void cls_reduce_kernel(const float* __restrict__ part, u16* __restrict__ y) {
    int bh = blockIdx.x;
    int b = bh / HEADS, hh = bh % HEADS;
    int d = threadIdx.x;   // 64
    float gm = -1e30f;
#pragma unroll
    for (int c = 0; c < CLS_NC; c++)
        gm = fmaxf(gm, part[((size_t)bh * CLS_NC + c) * 66]);
    float tot = 0.f, pv = 0.f;
#pragma unroll
    for (int c = 0; c < CLS_NC; c++) {
        const float* pp = part + ((size_t)bh * CLS_NC + c) * 66;
        float w = fast_exp2(pp[0] - gm);
        tot += pp[1] * w;
        pv  += pp[2 + d] * w;
    }
    y[(size_t)(b * NN) * C + hh * HD + d] = f2b(pv / tot);
}

// ---------------- fused repack K + V ----------------
__global__ void repack_kv_kernel(const u16* __restrict__ qkv,
                                 u16* __restrict__ Kb, u16* __restrict__ Vt) {
    const int NK = 24 * NF * 208 * 8;       // 319488
    const int NV = 24 * NF * 64 * 28;       // 344064
    int t = blockIdx.x * 256 + threadIdx.x;
    if (t < NK) {
        int d8 = t & 7;
        int rest = t >> 3;
        int n = rest % 208;
        rest /= 208;
        int f = rest % NF;
        int bh = rest / NF;
        int b = bh / HEADS, h = bh % HEADS;
        short8 v = {0, 0, 0, 0, 0, 0, 0, 0};
        if (n < SL)
            v = *(const short8*)(qkv + ((size_t)(b * NN) + 1 + f * SL + n) * 2304 + C + h * HD + d8 * 8);
        *(short8*)(Kb + (((size_t)bh * NF + f) * 208 + n) * 64 + d8 * 8) = v;
    } else {
        int u = t - NK;
        if (u >= NV) return;
        int n8 = u % 28;
        int rest = u / 28;
        int d = rest % 64;
        rest /= 64;
        int f = rest % NF;
        int bh = rest / NF;
        int b = bh / HEADS, h = bh % HEADS;
        int n0 = n8 * 8;
        const u16* src = qkv + ((size_t)(b * NN) + 1 + f * SL) * 2304 + 2 * C + h * HD + d;
        short8 v;
#pragma unroll
        for (int jj = 0; jj < 8; jj++) {
            int n = n0 + jj;
            v[jj] = (n < SL) ? (short)src[(size_t)n * 2304] : (short)0;
        }
        *(short8*)(Vt + (((size_t)bh * NF + f) * 64 + d) * 224 + n0) = v;
    }
}

// ---------------- MFMA spatial attention v8 (swapped QK^T, shuffle-PV, no P LDS) ----------
// P never touches LDS: lane (r16,kg) needs P[q=r16][k=32kc+8kg+j] which lives packed in
// lanes r16+32(kg&1) (j<4) and +16 (j>=4) at t=2kc+(kg>=2) -> cndmask select + 4 __shfl.
// LDS = K_f only (26.6KB); epilogue 16x72 bufs overlay dead K region after barrier 2.
__global__ void space_attn_mfma(
    const u16* __restrict__ qkv, const u16* __restrict__ Kb,
    const u16* __restrict__ Vt, u16* __restrict__ x1, u16* __restrict__ xd) {
    __shared__ u16 smem[13312];   // 26624 B: phase 1 = swizzled K_f; phase 2 = 4 x 2304B epi bufs
    int tid = threadIdx.x;
    int lane = tid & 63, wave = tid >> 6;
    int r16 = lane & 15, kg = lane >> 4;

    int n = blockIdx.x;
    int xcd = n & 7;
    int slot = n >> 3;
    int j = slot % 25;
    int gw = slot / 25;
    int bh = xcd * 3 + gw % 3;
    int f = gw / 3;
    int b = bh / HEADS, h = bh % HEADS;

    int strip = j * 4 + wave;
    bool act = strip < 98;
    if (!act) strip = 97;
    int q0 = strip * 16;

    const u16* qrow = qkv + ((size_t)(b * NN) + 1 + q0 + r16) * 2304 + h * HD + kg * 8;
    short8 aq0 = *(const short8*)(qrow);
    short8 aq1 = *(const short8*)(qrow + 32);

    const char* kb_g = (const char*)(Kb + ((size_t)bh * NF + f) * 208 * 64);
    for (int w = wave; w < 26; w += 4) {
        int p = w * 1024 + lane * 16;
        int row = p >> 7;
        int src = (p & ~127) | ((p & 127) ^ ((row & 7) << 4));
        gload_lds16(kb_g + src, (char*)smem + p);
    }
    __syncthreads();

    f32x4 acc[13];
#pragma unroll
    for (int t = 0; t < 13; t++) acc[t] = (f32x4){0.f, 0.f, 0.f, 0.f};
    const char* ksm = (const char*)smem;
    int swz = (r16 & 7) << 4;
    __builtin_amdgcn_s_setprio(1);
#pragma unroll
    for (int t = 0; t < 13; t++) {
        const char* krow = ksm + (t * 16 + r16) * 128;
        short8 bk0 = *(const short8*)(krow + ((kg * 16) ^ swz));
        short8 bk1 = *(const short8*)(krow + ((64 + kg * 16) ^ swz));
        acc[t] = __builtin_amdgcn_mfma_f32_16x16x32_bf16(bk0, aq0, acc[t], 0, 0, 0);
        acc[t] = __builtin_amdgcn_mfma_f32_16x16x32_bf16(bk1, aq1, acc[t], 0, 0, 0);
    }
    __builtin_amdgcn_s_setprio(0);

    // V prefetch for kc=0 (latency hides under softmax VALU)
    const u16* vbase = Vt + ((size_t)bh * NF + f) * 64 * 224;
    short8 vf[2][4];
#pragma unroll
    for (int dt = 0; dt < 4; dt++)
        vf[0][dt] = *(const short8*)(vbase + (dt * 16 + r16) * 224 + kg * 8);

    // no-max log2 softmax in registers; lane holds P[k=16t+4kg+r][q=r16]
    bool tailz = (kg >= 1);
    float ssum = 0.f;
#pragma unroll
    for (int t = 0; t < 13; t++) {
#pragma unroll
        for (int r = 0; r < 4; r++) {
            float p = (t == 12 && tailz) ? 0.f : fast_exp2(acc[t][r]);
            acc[t][r] = p;
            ssum += p;
        }
    }
    ssum += __shfl_xor(ssum, 16);
    ssum += __shfl_xor(ssum, 32);
    float inv = 1.f / ssum;

    // pack normalized P into u32 pairs (k ascending): w0[t]={4kg,4kg+1}, w1[t]={4kg+2,4kg+3}
    u32 w0[13], w1[13];
#pragma unroll
    for (int t = 0; t < 13; t++) {
        w0[t] = (u32)f2b(acc[t][0] * inv) | ((u32)f2b(acc[t][1] * inv) << 16);
        w1[t] = (u32)f2b(acc[t][2] * inv) | ((u32)f2b(acc[t][3] * inv) << 16);
    }

    // PV: A-frag via cross-lane shuffles; V reg double-buffer
    int src0 = r16 + ((kg & 1) << 5);   // lane holding kg'=2(kg&1)
    int src1 = src0 + 16;               // kg'=2(kg&1)+1
    bool thi = (kg >= 2);
    f32x4 o[4];
#pragma unroll
    for (int dt = 0; dt < 4; dt++) o[dt] = (f32x4){0.f, 0.f, 0.f, 0.f};
    __builtin_amdgcn_s_setprio(1);
#pragma unroll
    for (int kc = 0; kc < 7; kc++) {
        if (kc < 6) {
#pragma unroll
            for (int dt = 0; dt < 4; dt++)
                vf[(kc + 1) & 1][dt] = *(const short8*)(vbase + (dt * 16 + r16) * 224 + (kc + 1) * 32 + kg * 8);
        }
        u32 s0, s1;
        if (kc == 6) { s0 = thi ? 0u : w0[12]; s1 = thi ? 0u : w1[12]; }
        else         { s0 = thi ? w0[2 * kc + 1] : w0[2 * kc];
                       s1 = thi ? w1[2 * kc + 1] : w1[2 * kc]; }
        union { u32 u[4]; short8 s8; } pau;
        pau.u[0] = (u32)__shfl((int)s0, src0);
        pau.u[1] = (u32)__shfl((int)s1, src0);
        pau.u[2] = (u32)__shfl((int)s0, src1);
        pau.u[3] = (u32)__shfl((int)s1, src1);
#pragma unroll
        for (int dt = 0; dt < 4; dt++)
            o[dt] = __builtin_amdgcn_mfma_f32_16x16x32_bf16(pau.s8, vf[kc & 1][dt], o[dt], 0, 0, 0);
    }
    __builtin_amdgcn_s_setprio(0);

    // barrier: all waves done reading K; epilogue bufs overlay K region
    __syncthreads();
    if (act) {
        u16* eb = smem + wave * 1152;   // 16 rows x 72 stride (u16)
#pragma unroll
        for (int dt = 0; dt < 4; dt++)
#pragma unroll
            for (int r = 0; r < 4; r++)
                eb[(kg * 4 + r) * 72 + dt * 16 + r16] = f2b(o[dt][r]);
        u16* x1row = x1 + (((size_t)(b * SS + q0)) * NF + f) * C + h * HD;
        u16* xdrow = xd + ((size_t)(b * SS + q0)) * C + h * HD;
        int fbase = f * SL;
#pragma unroll
        for (int it = 0; it < 2; it++) {
            int c = it * 64 + lane;
            int qr = c >> 3, c8 = c & 7;
            short8 v8 = *(const short8*)(&eb[qr * 72 + c8 * 8]);
            *(short8*)(x1row + (size_t)qr * (NF * C) + c8 * 8) = v8;
            if ((unsigned)(q0 + qr - fbase) < (unsigned)SL)
                *(short8*)(xdrow + (size_t)qr * C + c8 * 8) = v8;
        }
    }
}

// ---------------- temporal attention (log2-domain softmax) ----------------
__global__ void attn2_kernel(const u16* __restrict__ q2, const u16* __restrict__ k2,
                             const u16* __restrict__ x1, u16* __restrict__ y) {
    int item = blockIdx.x * 4 + (threadIdx.x >> 6);
    if (item >= BB * HEADS * SS) return;
    int lane = threadIdx.x & 63;
    int s = item % SS;
    int bh = item / SS;
    int b = bh / HEADS, hh = bh % HEADS;
    size_t rowbs = (size_t)(b * SS + s);
    float qv = b2f(q2[rowbs * C + hh * HD + lane]) * QSCALE;
    float lg[NF];
#pragma unroll
    for (int f = 0; f < NF; f++) {
        float p = qv * b2f(k2[(rowbs * NF + f) * C + hh * HD + lane]);
        for (int off = 32; off; off >>= 1) p += __shfl_xor(p, off);
        lg[f] = p;
    }
    float m = lg[0];
#pragma unroll
    for (int f = 1; f < NF; f++) m = fmaxf(m, lg[f]);
    float sum = 0.f;
#pragma unroll
    for (int f = 0; f < NF; f++) { lg[f] = fast_exp2(lg[f] - m); sum += lg[f]; }
    float inv = 1.f / sum;
    float acc = 0.f;
#pragma unroll
    for (int f = 0; f < NF; f++) acc += lg[f] * b2f(x1[(rowbs * NF + f) * C + hh * HD + lane]);
    y[((size_t)(b * NN) + 1 + s) * C + hh * HD + lane] = f2b(acc * inv);
}

extern "C" void kernel_launch(void* const* d_in, const int* in_sizes, int n_in,
                              void* d_out, int out_size, void* d_ws, size_t ws_size,
                              hipStream_t stream) {
    const float* x    = (const float*)d_in[0];
    const float* g1   = (const float*)d_in[1];
    const float* b1   = (const float*)d_in[2];
    const float* Wqkv = (const float*)d_in[3];
    const float* Wq   = (const float*)d_in[4];
    const float* Wkv  = (const float*)d_in[5];
    const float* Wp   = (const float*)d_in[6];
    const float* bp   = (const float*)d_in[7];
    const float* g2   = (const float*)d_in[8];
    const float* b2_  = (const float*)d_in[9];
    const float* W1   = (const float*)d_in[10];
    const float* bf1  = (const float*)d_in[11];
    const float* W2   = (const float*)d_in[12];
    const float* bf2  = (const float*)d_in[13];
    float* out = (float*)d_out;

    // workspace layout (u16 elements)
    u16* us     = (u16*)d_ws;
    u16* xn_b   = us;                    // M1*768    (reused as hn after LN2)
    u16* qkv_b  = xn_b   + 2409984;      // M1*2304
    u16* Wt_qkv = qkv_b  + 7229952;      // 2304*768
    u16* Wt_q   = Wt_qkv + 1769472;      // 768*768
    u16* Wt_kv  = Wt_q   + 589824;       // 768*768 (first half of Wkv)
    u16* Wt_p   = Wt_kv  + 589824;       // 768*768
    u16* W1t    = Wt_p   + 589824;       // 3072*768
    u16* W2t    = W1t    + 2359296;      // 768*3072
    u16* Kb     = W2t    + 2359296;      // 24*8*208*64
    u16* Vt     = Kb     + 2555904;      // 24*8*64*224
    u16* x1b    = Vt     + 2752512;      // B*S*F*C
    u16* xdb    = x1b    + 19267584;     // B*S*C
    u16* q2b    = xdb    + 2408448;      // B*S*C
    u16* k2b    = q2b    + 2408448;      // B*S*F*C
    u16* y_b    = k2b    + 19267584;     // B*N*C
    u16* a1b    = y_b    + 2409984;      // B*N*HID
    float* cls_ws   = (float*)(a1b + 9639936);     // 24*7*66 floats
    float* fc2_part = cls_ws + 24 * 7 * 66;        // 2 * M1*768 floats

    const int M1 = BB * NN;       // 3138
    const int M2 = BB * SS;       // 3136
    const int M3 = BB * SS * NF;  // 25088

    // 0. fused weight transpose + bf16 convert (one launch)
    wtrans_all_kernel<<<2016, 256, 0, stream>>>(Wqkv, Wq, Wkv, Wp, W1, W2,
                                                Wt_qkv, Wt_q, Wt_kv, Wt_p, W1t, W2t);
    // 1. LN1 -> bf16
    ln_kernel<<<M1, 256, 0, stream>>>(x, g1, b1, xn_b, M1);
    // 2. qkv_b = xn_b @ Wqkv (bf16; q cols pre-scaled) — 128x128, 8 waves, 450 blocks
    gemm_bf16<3, 128, 128, 8><<<18 * 25, 512, 0, stream>>>(
        xn_b, Wt_qkv, nullptr, nullptr, qkv_b, M1, 2304, 768, 768, 768, 18);
    // 3. fused repack K + V
    repack_kv_kernel<<<(24 * NF * 208 * 8 + 24 * NF * 64 * 28 + 255) / 256, 256, 0, stream>>>(
        qkv_b, Kb, Vt);
    // 4. cls attention (two-pass flash-style) -> y_b row 0
    cls_partial_kernel<<<dim3(CLS_NC, BB * HEADS), 256, 0, stream>>>(qkv_b, cls_ws);
    cls_reduce_kernel<<<BB * HEADS, 64, 0, stream>>>(cls_ws, y_b);
    // 5. spatial attention -> x1b + fused diag gather -> xdb (shuffle-PV v8)
    space_attn_mfma<<<4800, 256, 0, stream>>>(qkv_b, Kb, Vt, x1b, xdb);
    // 6. q2 = xd @ Wq — 64x64, 4 waves, 588 blocks
    gemm_bf16<0, 64, 64, 4><<<12 * 49, 256, 0, stream>>>(
        xdb, Wt_q, nullptr, nullptr, q2b, M2, 768, 768, 768, 768, 12);
    // 7. k2 = x1 @ Wkv[:, :C] — 128x128, 8 waves, 1176 blocks
    gemm_bf16<0, 128, 128, 8><<<6 * 196, 512, 0, stream>>>(
        x1b, Wt_kv, nullptr, nullptr, k2b, M3, 768, 768, 768, 768, 6);
    // 8. temporal attention -> y_b rows 1..S
    attn2_kernel<<<(BB * HEADS * SS + 3) / 4, 256, 0, stream>>>(q2b, k2b, x1b, y_b);
    // 9. proj: out = y_b @ Wp + bp + x (f32) — 64x64, 4 waves, 600 blocks
    gemm_bf16<2, 64, 64, 4><<<12 * 50, 256, 0, stream>>>(
        y_b, Wt_p, bp, x, out, M1, 768, 768, 768, 768, 12);
    // 10. LN2 -> bf16 (reuse xn_b)
    ln_kernel<<<M1, 256, 0, stream>>>(out, g2, b2_, xn_b, M1);
    // 11. fc1 + exact GELU -> bf16 — 128x128, 8 waves, 600 blocks
    gemm_bf16<1, 128, 128, 8><<<24 * 25, 512, 0, stream>>>(
        xn_b, W1t, bf1, nullptr, a1b, M1, 3072, 768, 768, 768, 24);
    // 12. fc2 split-K=2: partials (f32) — 128x64, 4 waves, 600 blocks; then merge
    gemm_bf16<4, 128, 64, 4><<<12 * 25 * 2, 256, 0, stream>>>(
        a1b, W2t, nullptr, nullptr, fc2_part, M1, 768, 1536, 3072, 3072, 12);
    fc2_merge_kernel<<<(BB * NN * (C / 4) + 255) / 256, 256, 0, stream>>>(
        fc2_part, bf2, out);
}

// Round 23
// 269.365 us; speedup vs baseline: 1.0320x; 1.0320x over previous
//
#include <hip/hip_runtime.h>
#include <hip/hip_bf16.h>
#include <math.h>

#define C     768
#define HEADS 12
#define HD    64
#define NF    8
#define SL    196
#define BB    2
#define NN    1569   // 1 + NF*SL
#define SS    1568   // NF*SL
#define HID   3072
#define CLS_CH 256
#define CLS_NC 7     // ceil(NN / CLS_CH)
#define QSCALE 0.18033688011112042f   // 0.125 * log2(e); scores live in log2 domain

typedef __attribute__((ext_vector_type(8))) short short8;
typedef __attribute__((ext_vector_type(4))) float f32x4;
typedef unsigned short u16;
typedef unsigned int u32;

__device__ inline float fast_exp2(float x) { return __builtin_amdgcn_exp2f(x); }

__device__ inline u16 f2b(float f) {
    __hip_bfloat16 h = __float2bfloat16(f);   // HW v_cvt path (RNE)
    return *reinterpret_cast<u16*>(&h);
}
__device__ inline float b2f(u16 u) {
    union { unsigned u; float f; } v; v.u = ((unsigned)u) << 16;
    return v.f;
}

__device__ inline void gload_lds16(const void* g, void* l) {
    __builtin_amdgcn_global_load_lds(
        (const __attribute__((address_space(1))) void*)g,
        (__attribute__((address_space(3))) void*)l, 16, 0, 0);
}

// ---------------- LayerNorm: f32 in -> bf16 out ----------------
__global__ void ln_kernel(const float* __restrict__ x, const float* __restrict__ g,
                          const float* __restrict__ b, u16* __restrict__ out, int rows) {
    int row = blockIdx.x;
    if (row >= rows) return;
    const float* xr = x + (size_t)row * C;
    int tid = threadIdx.x;
    float v[3];
    float sum = 0.f, sumsq = 0.f;
#pragma unroll
    for (int i = 0; i < 3; i++) {
        v[i] = xr[tid + 256 * i];
        sum += v[i]; sumsq += v[i] * v[i];
    }
    __shared__ float s1[4], s2[4];
    for (int off = 32; off; off >>= 1) {
        sum   += __shfl_xor(sum, off);
        sumsq += __shfl_xor(sumsq, off);
    }
    int wave = tid >> 6, lane = tid & 63;
    if (lane == 0) { s1[wave] = sum; s2[wave] = sumsq; }
    __syncthreads();
    sum   = s1[0] + s1[1] + s1[2] + s1[3];
    sumsq = s2[0] + s2[1] + s2[2] + s2[3];
    float mu  = sum / C;
    float var = sumsq / C - mu * mu;
    float rstd = rsqrtf(fmaxf(var, 0.f) + 1e-5f);
    u16* outr = out + (size_t)row * C;
#pragma unroll
    for (int i = 0; i < 3; i++) {
        int c = tid + 256 * i;
        outr[c] = f2b((v[i] - mu) * rstd * g[c] + b[c]);
    }
}

// ---------------- fused weight transpose+convert (all 6 weights, one launch) ----------------
__global__ void wtrans_all_kernel(
    const float* __restrict__ Wqkv, const float* __restrict__ Wq,
    const float* __restrict__ Wkv,  const float* __restrict__ Wp,
    const float* __restrict__ W1,   const float* __restrict__ W2,
    u16* Tqkv, u16* Tq, u16* Tkv, u16* Tp, u16* T1, u16* T2) {
    __shared__ float tile[64][65];
    int bid = blockIdx.x;
    const float* W; u16* Wt; int K, ldb, gx;
    if (bid < 432)       { W = Wqkv; Wt = Tqkv; K = 768;  ldb = 2304; gx = 36; }
    else if (bid < 576)  { W = Wq;   Wt = Tq;   K = 768;  ldb = 768;  gx = 12; bid -= 432; }
    else if (bid < 720)  { W = Wkv;  Wt = Tkv;  K = 768;  ldb = 1536; gx = 12; bid -= 576; }
    else if (bid < 864)  { W = Wp;   Wt = Tp;   K = 768;  ldb = 768;  gx = 12; bid -= 720; }
    else if (bid < 1440) { W = W1;   Wt = T1;   K = 768;  ldb = 3072; gx = 48; bid -= 864; }
    else                 { W = W2;   Wt = T2;   K = 3072; ldb = 768;  gx = 12; bid -= 1440; }
    int nb = (bid % gx) * 64, kb = (bid / gx) * 64;
    int tx = threadIdx.x & 63, ty = threadIdx.x >> 6;
#pragma unroll
    for (int i = 0; i < 64; i += 4)
        tile[ty + i][tx] = W[(size_t)(kb + ty + i) * ldb + nb + tx];
    __syncthreads();
#pragma unroll
    for (int i = 0; i < 64; i += 4)
        Wt[(size_t)(nb + ty + i) * K + kb + tx] = f2b(tile[tx][ty + i]);
}

// ---------------- bf16 MFMA GEMM (2-phase dbuf, XCD-swizzled 1-D grid) ----------------
// Tiled BM x BN with WAVES waves (2 rows x WAVES/2 cols); wave tile (BM/2) x (BN/(WAVES/2)).
// MODE 0: bf16 out. MODE 1: bf16 out, bias + exact GELU. MODE 2: f32 out, bias + resid.
// MODE 3: bf16 out, cols < 768 scaled by QSCALE. MODE 4: split-K f32 partials.
template<int MODE, int BM, int BN, int WAVES>
__global__ __launch_bounds__(WAVES * 64) void gemm_bf16(
    const u16* __restrict__ A, const u16* __restrict__ Bt,
    const float* __restrict__ bias, const float* resid, void* Cout,
    int M, int N, int K, int lda, int ldb, int gx) {
    constexpr int WCOLS = WAVES / 2;
    constexpr int WBN   = BN / WCOLS;
    constexpr int MT    = BM / 32;
    constexpr int NT    = WBN / 16;
    constexpr int ACH   = BM * 4;
    constexpr int TCH   = (BM + BN) * 4;
    constexpr int HALF  = (BM + BN) * 64;
    __shared__ char smem[2 * HALF];
    int tid = threadIdx.x, lane = tid & 63, wave = tid >> 6;
    int wr = wave / WCOLS, wc = wave % WCOLS;
    int r16 = lane & 15, kg = lane >> 4;

    int nwg = gridDim.x, orig = blockIdx.x;
    int qq = nwg >> 3, rr = nwg & 7, xcd = orig & 7, lid = orig >> 3;
    int wg = (xcd < rr ? xcd * (qq + 1) : rr * (qq + 1) + (xcd - rr) * qq) + lid;
    int bx = wg % gx, by = wg / gx;
    if constexpr (MODE == 4) {
        int mt_ = (M + BM - 1) / BM;
        int chunk = by / mt_; by -= chunk * mt_;
        A    += (size_t)chunk * K;
        Bt   += (size_t)chunk * K;
        Cout  = (void*)((float*)Cout + (size_t)chunk * ((size_t)M * N));
    }
    int row0 = by * BM, col0 = bx * BN;

    f32x4 acc[MT][NT];
#pragma unroll
    for (int mt = 0; mt < MT; mt++)
#pragma unroll
        for (int nt = 0; nt < NT; nt++) acc[mt][nt] = (f32x4){0.f, 0.f, 0.f, 0.f};

    auto stage = [&](char* dstbase, int ks) {
        int k0 = ks << 5;
#pragma unroll
        for (int it = 0; it < TCH / (WAVES * 64); it++) {
            int c = it * (WAVES * 64) + tid;
            const u16* src;
            if (c < ACH) {
                int ml = c >> 2, s = c & 3;
                int kgs = s ^ ((ml >> 1) & 3);
                int gm = row0 + ml; if (gm >= M) gm = M - 1;
                src = A + (size_t)gm * lda + k0 + kgs * 8;
            } else {
                int cc = c - ACH;
                int nl = cc >> 2, s = cc & 3;
                int kgs = s ^ ((nl >> 1) & 3);
                src = Bt + (size_t)(col0 + nl) * ldb + k0 + kgs * 8;
            }
            gload_lds16(src, dstbase + it * (WAVES * 1024) + wave * 1024);
        }
    };

    int nsteps = K >> 5;
    stage(smem, 0);
    __syncthreads();
    for (int ks = 0; ks < nsteps; ks++) {
        char* curb = smem + (ks & 1) * HALF;
        if (ks + 1 < nsteps) stage(smem + ((ks + 1) & 1) * HALF, ks + 1);
        short8 af[MT], bfr[NT];
#pragma unroll
        for (int mt = 0; mt < MT; mt++) {
            int ml = wr * (BM / 2) + mt * 16 + r16;
            af[mt] = *(const short8*)(curb + ml * 64 + ((kg ^ ((ml >> 1) & 3)) << 4));
        }
#pragma unroll
        for (int nt = 0; nt < NT; nt++) {
            int nl = wc * WBN + nt * 16 + r16;
            bfr[nt] = *(const short8*)(curb + BM * 64 + nl * 64 + ((kg ^ ((nl >> 1) & 3)) << 4));
        }
        __builtin_amdgcn_s_setprio(1);
#pragma unroll
        for (int mt = 0; mt < MT; mt++)
#pragma unroll
            for (int nt = 0; nt < NT; nt++)
                acc[mt][nt] = __builtin_amdgcn_mfma_f32_16x16x32_bf16(af[mt], bfr[nt], acc[mt][nt], 0, 0, 0);
        __builtin_amdgcn_s_setprio(0);
        __syncthreads();
    }
#pragma unroll
    for (int mt = 0; mt < MT; mt++) {
#pragma unroll
        for (int r2 = 0; r2 < 4; r2++) {
            int gm = row0 + wr * (BM / 2) + mt * 16 + kg * 4 + r2;
            if (gm >= M) continue;
#pragma unroll
            for (int nt = 0; nt < NT; nt++) {
                int gn = col0 + wc * WBN + nt * 16 + r16;
                float v = acc[mt][nt][r2];
                if constexpr (MODE == 1) {
                    v += bias[gn];
                    v = 0.5f * v * (1.f + erff(v * 0.70710678118f));
                }
                if constexpr (MODE == 2) {
                    v += bias[gn] + resid[(size_t)gm * N + gn];
                    ((float*)Cout)[(size_t)gm * N + gn] = v;
                } else if constexpr (MODE == 4) {
                    ((float*)Cout)[(size_t)gm * N + gn] = v;
                } else {
                    if constexpr (MODE == 3) { if (gn < 768) v *= QSCALE; }
                    ((u16*)Cout)[(size_t)gm * N + gn] = f2b(v);
                }
            }
        }
    }
}

// ---------------- fc2 split-K=2 merge: out += p0+p1 + bias (float4) ----------------
__global__ void fc2_merge_kernel(const float* __restrict__ p,
                                 const float* __restrict__ bias, float* __restrict__ out) {
    int i = blockIdx.x * 256 + threadIdx.x;
    int total = BB * NN * (C / 4);
    if (i >= total) return;
    int c4 = i % (C / 4);
    size_t stride = (size_t)BB * NN * (C / 4);
    float4 bb = ((const float4*)bias)[c4];
    float4 a0 = ((const float4*)p)[i];
    float4 a1 = ((const float4*)p)[i + stride];
    float4 o  = ((float4*)out)[i];
    o.x += a0.x + a1.x + bb.x;
    o.y += a0.y + a1.y + bb.y;
    o.z += a0.z + a1.z + bb.z;
    o.w += a0.w + a1.w + bb.w;
    ((float4*)out)[i] = o;
}

// ---------------- cls attention pass 1 (q pre-scaled; log2-domain softmax) ----------------
__global__ void cls_partial_kernel(const u16* __restrict__ qkv, float* __restrict__ part) {
    int c = blockIdx.x, bh = blockIdx.y;
    int b = bh / HEADS, hh = bh % HEADS;
    int tid = threadIdx.x;
    int wave = tid >> 6, lane = tid & 63;
    __shared__ float s_q[HD];
    __shared__ float s_sc[CLS_CH];
    __shared__ float sm[4], ss[4];
    __shared__ float sacc[4][HD];
    if (tid < HD) s_q[tid] = b2f(qkv[(size_t)(b * NN) * 2304 + hh * HD + tid]);
    __syncthreads();

    int j0 = c * CLS_CH;
    int j = j0 + tid;
    float sc = -1e30f;
    if (j < NN) {
        const short8* kp = (const short8*)(qkv + ((size_t)(b * NN) + j) * 2304 + C + hh * HD);
        float acc = 0.f;
#pragma unroll
        for (int u = 0; u < 8; u++) {
            short8 kv = kp[u];
#pragma unroll
            for (int e = 0; e < 8; e++) acc += s_q[u * 8 + e] * b2f((u16)kv[e]);
        }
        sc = acc;
    }
    float m = sc;
    for (int off = 32; off; off >>= 1) m = fmaxf(m, __shfl_xor(m, off));
    if (lane == 0) sm[wave] = m;
    __syncthreads();
    m = fmaxf(fmaxf(sm[0], sm[1]), fmaxf(sm[2], sm[3]));
    float e = (j < NN) ? fast_exp2(sc - m) : 0.f;
    s_sc[tid] = e;
    float su = e;
    for (int off = 32; off; off >>= 1) su += __shfl_xor(su, off);
    if (lane == 0) ss[wave] = su;
    __syncthreads();
    float ssum = ss[0] + ss[1] + ss[2] + ss[3];

    int jj = tid >> 6, d = tid & 63;
    int jmax = NN - j0; if (jmax > CLS_CH) jmax = CLS_CH;
    const u16* vcol = qkv + ((size_t)(b * NN) + j0) * 2304 + 2 * C + hh * HD + d;
    float acc = 0.f;
    for (int t = jj; t < jmax; t += 4)
        acc += s_sc[t] * b2f(vcol[(size_t)t * 2304]);
    sacc[jj][d] = acc;
    __syncthreads();
    if (tid < HD) {
        float pv = sacc[0][tid] + sacc[1][tid] + sacc[2][tid] + sacc[3][tid];
        float* pp = part + ((size_t)bh * CLS_NC + c) * 66;
        pp[2 + tid] = pv;
        if (tid == 0) { pp[0] = m; pp[1] = ssum; }
    }
}

// ---------------- cls attention pass 2: merge chunk partials (log2 domain) ----------------
__global__ void cls_reduce_kernel(const float* __restrict__ part, u16* __restrict__ y) {
    int bh = blockIdx.x;
    int b = bh / HEADS, hh = bh % HEADS;
    int d = threadIdx.x;   // 64
    float gm = -1e30f;
#pragma unroll
    for (int c = 0; c < CLS_NC; c++)
        gm = fmaxf(gm, part[((size_t)bh * CLS_NC + c) * 66]);
    float tot = 0.f, pv = 0.f;
#pragma unroll
    for (int c = 0; c < CLS_NC; c++) {
        const float* pp = part + ((size_t)bh * CLS_NC + c) * 66;
        float w = fast_exp2(pp[0] - gm);
        tot += pp[1] * w;
        pv  += pp[2 + d] * w;
    }
    y[(size_t)(b * NN) * C + hh * HD + d] = f2b(pv / tot);
}

// ---------------- fused repack K + V ----------------
__global__ void repack_kv_kernel(const u16* __restrict__ qkv,
                                 u16* __restrict__ Kb, u16* __restrict__ Vt) {
    const int NK = 24 * NF * 208 * 8;       // 319488
    const int NV = 24 * NF * 64 * 28;       // 344064
    int t = blockIdx.x * 256 + threadIdx.x;
    if (t < NK) {
        int d8 = t & 7;
        int rest = t >> 3;
        int n = rest % 208;
        rest /= 208;
        int f = rest % NF;
        int bh = rest / NF;
        int b = bh / HEADS, h = bh % HEADS;
        short8 v = {0, 0, 0, 0, 0, 0, 0, 0};
        if (n < SL)
            v = *(const short8*)(qkv + ((size_t)(b * NN) + 1 + f * SL + n) * 2304 + C + h * HD + d8 * 8);
        *(short8*)(Kb + (((size_t)bh * NF + f) * 208 + n) * 64 + d8 * 8) = v;
    } else {
        int u = t - NK;
        if (u >= NV) return;
        int n8 = u % 28;
        int rest = u / 28;
        int d = rest % 64;
        rest /= 64;
        int f = rest % NF;
        int bh = rest / NF;
        int b = bh / HEADS, h = bh % HEADS;
        int n0 = n8 * 8;
        const u16* src = qkv + ((size_t)(b * NN) + 1 + f * SL) * 2304 + 2 * C + h * HD + d;
        short8 v;
#pragma unroll
        for (int jj = 0; jj < 8; jj++) {
            int n = n0 + jj;
            v[jj] = (n < SL) ? (short)src[(size_t)n * 2304] : (short)0;
        }
        *(short8*)(Vt + (((size_t)bh * NF + f) * 64 + d) * 224 + n0) = v;
    }
}

// ---------------- MFMA spatial attention v9 (dual-strip, shared V, shuffle-PV) ----------
// Each wave processes TWO 16-query strips per K-stage: one stage+barrier pair serves 8
// strips/block (grid 2496). V fragments loaded once per kc and used by both strips
// (interleaved independent MFMA chains). Epilogue: 2 per-wave bufs overlay dead K region.
__global__ void space_attn_mfma(
    const u16* __restrict__ qkv, const u16* __restrict__ Kb,
    const u16* __restrict__ Vt, u16* __restrict__ x1, u16* __restrict__ xd) {
    __shared__ u16 smem[13312];   // 26624 B: phase 1 = swizzled K_f; phase 2 = 4 x 4608B epi bufs
    int tid = threadIdx.x;
    int lane = tid & 63, wave = tid >> 6;
    int r16 = lane & 15, kg = lane >> 4;

    // XCD-aware decode: n = xcd + 8*(gw*13 + j); 8 strips per block (4 waves x 2)
    int n = blockIdx.x;
    int xcd = n & 7;
    int slot = n >> 3;
    int j = slot % 13;
    int gw = slot / 13;            // 0..23
    int bh = xcd * 3 + gw % 3;
    int f = gw / 3;
    int b = bh / HEADS, h = bh % HEADS;

    int sA = j * 8 + wave * 2, sB = sA + 1;
    bool actA = sA < 98, actB = sB < 98;
    int q0A = (actA ? sA : 97) * 16;
    int q0B = (actB ? sB : 97) * 16;

    // Q loads for BOTH strips up-front (latency hides under K staging)
    const u16* qrowA = qkv + ((size_t)(b * NN) + 1 + q0A + r16) * 2304 + h * HD + kg * 8;
    const u16* qrowB = qkv + ((size_t)(b * NN) + 1 + q0B + r16) * 2304 + h * HD + kg * 8;
    short8 aqA0 = *(const short8*)(qrowA);
    short8 aqA1 = *(const short8*)(qrowA + 32);
    short8 aqB0 = *(const short8*)(qrowB);
    short8 aqB1 = *(const short8*)(qrowB + 32);

    // stage K_f into LDS (linear dest, pre-swizzled source)
    const char* kb_g = (const char*)(Kb + ((size_t)bh * NF + f) * 208 * 64);
    for (int w = wave; w < 26; w += 4) {
        int p = w * 1024 + lane * 16;
        int row = p >> 7;
        int src = (p & ~127) | ((p & 127) ^ ((row & 7) << 4));
        gload_lds16(kb_g + src, (char*)smem + p);
    }
    __syncthreads();

    const char* ksm = (const char*)smem;
    int swz = (r16 & 7) << 4;
    bool tailz = (kg >= 1);
    const u16* vbase = Vt + ((size_t)bh * NF + f) * 64 * 224;

    f32x4 acc[13];
    u32 w0A[13], w1A[13], w0B[13], w1B[13];

    // ---- strip A: QK^T + softmax + pack ----
#pragma unroll
    for (int t = 0; t < 13; t++) acc[t] = (f32x4){0.f, 0.f, 0.f, 0.f};
    __builtin_amdgcn_s_setprio(1);
#pragma unroll
    for (int t = 0; t < 13; t++) {
        const char* krow = ksm + (t * 16 + r16) * 128;
        short8 bk0 = *(const short8*)(krow + ((kg * 16) ^ swz));
        short8 bk1 = *(const short8*)(krow + ((64 + kg * 16) ^ swz));
        acc[t] = __builtin_amdgcn_mfma_f32_16x16x32_bf16(bk0, aqA0, acc[t], 0, 0, 0);
        acc[t] = __builtin_amdgcn_mfma_f32_16x16x32_bf16(bk1, aqA1, acc[t], 0, 0, 0);
    }
    __builtin_amdgcn_s_setprio(0);
    // V prefetch kc=0 (hides under softmax A + QK B)
    short8 vf[2][4];
#pragma unroll
    for (int dt = 0; dt < 4; dt++)
        vf[0][dt] = *(const short8*)(vbase + (dt * 16 + r16) * 224 + kg * 8);
    {
        float ssum = 0.f;
#pragma unroll
        for (int t = 0; t < 13; t++)
#pragma unroll
            for (int r = 0; r < 4; r++) {
                float p = (t == 12 && tailz) ? 0.f : fast_exp2(acc[t][r]);
                acc[t][r] = p;
                ssum += p;
            }
        ssum += __shfl_xor(ssum, 16);
        ssum += __shfl_xor(ssum, 32);
        float inv = 1.f / ssum;
#pragma unroll
        for (int t = 0; t < 13; t++) {
            w0A[t] = (u32)f2b(acc[t][0] * inv) | ((u32)f2b(acc[t][1] * inv) << 16);
            w1A[t] = (u32)f2b(acc[t][2] * inv) | ((u32)f2b(acc[t][3] * inv) << 16);
        }
    }

    // ---- strip B: QK^T + softmax + pack (reuses acc regs) ----
#pragma unroll
    for (int t = 0; t < 13; t++) acc[t] = (f32x4){0.f, 0.f, 0.f, 0.f};
    __builtin_amdgcn_s_setprio(1);
#pragma unroll
    for (int t = 0; t < 13; t++) {
        const char* krow = ksm + (t * 16 + r16) * 128;
        short8 bk0 = *(const short8*)(krow + ((kg * 16) ^ swz));
        short8 bk1 = *(const short8*)(krow + ((64 + kg * 16) ^ swz));
        acc[t] = __builtin_amdgcn_mfma_f32_16x16x32_bf16(bk0, aqB0, acc[t], 0, 0, 0);
        acc[t] = __builtin_amdgcn_mfma_f32_16x16x32_bf16(bk1, aqB1, acc[t], 0, 0, 0);
    }
    __builtin_amdgcn_s_setprio(0);
    {
        float ssum = 0.f;
#pragma unroll
        for (int t = 0; t < 13; t++)
#pragma unroll
            for (int r = 0; r < 4; r++) {
                float p = (t == 12 && tailz) ? 0.f : fast_exp2(acc[t][r]);
                acc[t][r] = p;
                ssum += p;
            }
        ssum += __shfl_xor(ssum, 16);
        ssum += __shfl_xor(ssum, 32);
        float inv = 1.f / ssum;
#pragma unroll
        for (int t = 0; t < 13; t++) {
            w0B[t] = (u32)f2b(acc[t][0] * inv) | ((u32)f2b(acc[t][1] * inv) << 16);
            w1B[t] = (u32)f2b(acc[t][2] * inv) | ((u32)f2b(acc[t][3] * inv) << 16);
        }
    }

    // ---- PV for BOTH strips, V loaded once per kc ----
    int src0 = r16 + ((kg & 1) << 5);
    int src1 = src0 + 16;
    bool thi = (kg >= 2);
    f32x4 oA[4], oB[4];
#pragma unroll
    for (int dt = 0; dt < 4; dt++) { oA[dt] = (f32x4){0.f, 0.f, 0.f, 0.f}; oB[dt] = (f32x4){0.f, 0.f, 0.f, 0.f}; }
    __builtin_amdgcn_s_setprio(1);
#pragma unroll
    for (int kc = 0; kc < 7; kc++) {
        if (kc < 6) {
#pragma unroll
            for (int dt = 0; dt < 4; dt++)
                vf[(kc + 1) & 1][dt] = *(const short8*)(vbase + (dt * 16 + r16) * 224 + (kc + 1) * 32 + kg * 8);
        }
        u32 a0, a1, b0, b1;
        if (kc == 6) {
            a0 = thi ? 0u : w0A[12]; a1 = thi ? 0u : w1A[12];
            b0 = thi ? 0u : w0B[12]; b1 = thi ? 0u : w1B[12];
        } else {
            a0 = thi ? w0A[2 * kc + 1] : w0A[2 * kc];
            a1 = thi ? w1A[2 * kc + 1] : w1A[2 * kc];
            b0 = thi ? w0B[2 * kc + 1] : w0B[2 * kc];
            b1 = thi ? w1B[2 * kc + 1] : w1B[2 * kc];
        }
        union { u32 u[4]; short8 s8; } pA, pB;
        pA.u[0] = (u32)__shfl((int)a0, src0);
        pA.u[1] = (u32)__shfl((int)a1, src0);
        pA.u[2] = (u32)__shfl((int)a0, src1);
        pA.u[3] = (u32)__shfl((int)a1, src1);
        pB.u[0] = (u32)__shfl((int)b0, src0);
        pB.u[1] = (u32)__shfl((int)b1, src0);
        pB.u[2] = (u32)__shfl((int)b0, src1);
        pB.u[3] = (u32)__shfl((int)b1, src1);
#pragma unroll
        for (int dt = 0; dt < 4; dt++) {
            oA[dt] = __builtin_amdgcn_mfma_f32_16x16x32_bf16(pA.s8, vf[kc & 1][dt], oA[dt], 0, 0, 0);
            oB[dt] = __builtin_amdgcn_mfma_f32_16x16x32_bf16(pB.s8, vf[kc & 1][dt], oB[dt], 0, 0, 0);
        }
    }
    __builtin_amdgcn_s_setprio(0);

    // barrier: all waves done reading K; epilogue bufs overlay K region
    __syncthreads();
    u16* ebA = smem + wave * 2304;          // 16 x 72 (u16)
    u16* ebB = ebA + 1152;
    int fbase = f * SL;
#pragma unroll
    for (int dt = 0; dt < 4; dt++)
#pragma unroll
        for (int r = 0; r < 4; r++) {
            ebA[(kg * 4 + r) * 72 + dt * 16 + r16] = f2b(oA[dt][r]);
            ebB[(kg * 4 + r) * 72 + dt * 16 + r16] = f2b(oB[dt][r]);
        }
    if (actA) {
        u16* x1row = x1 + (((size_t)(b * SS + q0A)) * NF + f) * C + h * HD;
        u16* xdrow = xd + ((size_t)(b * SS + q0A)) * C + h * HD;
#pragma unroll
        for (int it = 0; it < 2; it++) {
            int c = it * 64 + lane;
            int qr = c >> 3, c8 = c & 7;
            short8 v8 = *(const short8*)(&ebA[qr * 72 + c8 * 8]);
            *(short8*)(x1row + (size_t)qr * (NF * C) + c8 * 8) = v8;
            if ((unsigned)(q0A + qr - fbase) < (unsigned)SL)
                *(short8*)(xdrow + (size_t)qr * C + c8 * 8) = v8;
        }
    }
    if (actB) {
        u16* x1row = x1 + (((size_t)(b * SS + q0B)) * NF + f) * C + h * HD;
        u16* xdrow = xd + ((size_t)(b * SS + q0B)) * C + h * HD;
#pragma unroll
        for (int it = 0; it < 2; it++) {
            int c = it * 64 + lane;
            int qr = c >> 3, c8 = c & 7;
            short8 v8 = *(const short8*)(&ebB[qr * 72 + c8 * 8]);
            *(short8*)(x1row + (size_t)qr * (NF * C) + c8 * 8) = v8;
            if ((unsigned)(q0B + qr - fbase) < (unsigned)SL)
                *(short8*)(xdrow + (size_t)qr * C + c8 * 8) = v8;
        }
    }
}

// ---------------- temporal attention (log2-domain softmax) ----------------
__global__ void attn2_kernel(const u16* __restrict__ q2, const u16* __restrict__ k2,
                             const u16* __restrict__ x1, u16* __restrict__ y) {
    int item = blockIdx.x * 4 + (threadIdx.x >> 6);
    if (item >= BB * HEADS * SS) return;
    int lane = threadIdx.x & 63;
    int s = item % SS;
    int bh = item / SS;
    int b = bh / HEADS, hh = bh % HEADS;
    size_t rowbs = (size_t)(b * SS + s);
    float qv = b2f(q2[rowbs * C + hh * HD + lane]) * QSCALE;
    float lg[NF];
#pragma unroll
    for (int f = 0; f < NF; f++) {
        float p = qv * b2f(k2[(rowbs * NF + f) * C + hh * HD + lane]);
        for (int off = 32; off; off >>= 1) p += __shfl_xor(p, off);
        lg[f] = p;
    }
    float m = lg[0];
#pragma unroll
    for (int f = 1; f < NF; f++) m = fmaxf(m, lg[f]);
    float sum = 0.f;
#pragma unroll
    for (int f = 0; f < NF; f++) { lg[f] = fast_exp2(lg[f] - m); sum += lg[f]; }
    float inv = 1.f / sum;
    float acc = 0.f;
#pragma unroll
    for (int f = 0; f < NF; f++) acc += lg[f] * b2f(x1[(rowbs * NF + f) * C + hh * HD + lane]);
    y[((size_t)(b * NN) + 1 + s) * C + hh * HD + lane] = f2b(acc * inv);
}

extern "C" void kernel_launch(void* const* d_in, const int* in_sizes, int n_in,
                              void* d_out, int out_size, void* d_ws, size_t ws_size,
                              hipStream_t stream) {
    const float* x    = (const float*)d_in[0];
    const float* g1   = (const float*)d_in[1];
    const float* b1   = (const float*)d_in[2];
    const float* Wqkv = (const float*)d_in[3];
    const float* Wq   = (const float*)d_in[4];
    const float* Wkv  = (const float*)d_in[5];
    const float* Wp   = (const float*)d_in[6];
    const float* bp   = (const float*)d_in[7];
    const float* g2   = (const float*)d_in[8];
    const float* b2_  = (const float*)d_in[9];
    const float* W1   = (const float*)d_in[10];
    const float* bf1  = (const float*)d_in[11];
    const float* W2   = (const float*)d_in[12];
    const float* bf2  = (const float*)d_in[13];
    float* out = (float*)d_out;

    // workspace layout (u16 elements)
    u16* us     = (u16*)d_ws;
    u16* xn_b   = us;                    // M1*768    (reused as hn after LN2)
    u16* qkv_b  = xn_b   + 2409984;      // M1*2304
    u16* Wt_qkv = qkv_b  + 7229952;      // 2304*768
    u16* Wt_q   = Wt_qkv + 1769472;      // 768*768
    u16* Wt_kv  = Wt_q   + 589824;       // 768*768 (first half of Wkv)
    u16* Wt_p   = Wt_kv  + 589824;       // 768*768
    u16* W1t    = Wt_p   + 589824;       // 3072*768
    u16* W2t    = W1t    + 2359296;      // 768*3072
    u16* Kb     = W2t    + 2359296;      // 24*8*208*64
    u16* Vt     = Kb     + 2555904;      // 24*8*64*224
    u16* x1b    = Vt     + 2752512;      // B*S*F*C
    u16* xdb    = x1b    + 19267584;     // B*S*C
    u16* q2b    = xdb    + 2408448;      // B*S*C
    u16* k2b    = q2b    + 2408448;      // B*S*F*C
    u16* y_b    = k2b    + 19267584;     // B*N*C
    u16* a1b    = y_b    + 2409984;      // B*N*HID
    float* cls_ws   = (float*)(a1b + 9639936);     // 24*7*66 floats
    float* fc2_part = cls_ws + 24 * 7 * 66;        // 2 * M1*768 floats

    const int M1 = BB * NN;       // 3138
    const int M2 = BB * SS;       // 3136
    const int M3 = BB * SS * NF;  // 25088

    // 0. fused weight transpose + bf16 convert (one launch)
    wtrans_all_kernel<<<2016, 256, 0, stream>>>(Wqkv, Wq, Wkv, Wp, W1, W2,
                                                Wt_qkv, Wt_q, Wt_kv, Wt_p, W1t, W2t);
    // 1. LN1 -> bf16
    ln_kernel<<<M1, 256, 0, stream>>>(x, g1, b1, xn_b, M1);
    // 2. qkv_b = xn_b @ Wqkv (bf16; q cols pre-scaled) — 128x128, 8 waves, 450 blocks
    gemm_bf16<3, 128, 128, 8><<<18 * 25, 512, 0, stream>>>(
        xn_b, Wt_qkv, nullptr, nullptr, qkv_b, M1, 2304, 768, 768, 768, 18);
    // 3. fused repack K + V
    repack_kv_kernel<<<(24 * NF * 208 * 8 + 24 * NF * 64 * 28 + 255) / 256, 256, 0, stream>>>(
        qkv_b, Kb, Vt);
    // 4. cls attention (two-pass flash-style) -> y_b row 0
    cls_partial_kernel<<<dim3(CLS_NC, BB * HEADS), 256, 0, stream>>>(qkv_b, cls_ws);
    cls_reduce_kernel<<<BB * HEADS, 64, 0, stream>>>(cls_ws, y_b);
    // 5. spatial attention -> x1b + fused diag gather -> xdb (dual-strip v9)
    space_attn_mfma<<<2496, 256, 0, stream>>>(qkv_b, Kb, Vt, x1b, xdb);
    // 6. q2 = xd @ Wq — 64x64, 4 waves, 588 blocks
    gemm_bf16<0, 64, 64, 4><<<12 * 49, 256, 0, stream>>>(
        xdb, Wt_q, nullptr, nullptr, q2b, M2, 768, 768, 768, 768, 12);
    // 7. k2 = x1 @ Wkv[:, :C] — 128x128, 8 waves, 1176 blocks
    gemm_bf16<0, 128, 128, 8><<<6 * 196, 512, 0, stream>>>(
        x1b, Wt_kv, nullptr, nullptr, k2b, M3, 768, 768, 768, 768, 6);
    // 8. temporal attention -> y_b rows 1..S
    attn2_kernel<<<(BB * HEADS * SS + 3) / 4, 256, 0, stream>>>(q2b, k2b, x1b, y_b);
    // 9. proj: out = y_b @ Wp + bp + x (f32) — 64x64, 4 waves, 600 blocks
    gemm_bf16<2, 64, 64, 4><<<12 * 50, 256, 0, stream>>>(
        y_b, Wt_p, bp, x, out, M1, 768, 768, 768, 768, 12);
    // 10. LN2 -> bf16 (reuse xn_b)
    ln_kernel<<<M1, 256, 0, stream>>>(out, g2, b2_, xn_b, M1);
    // 11. fc1 + exact GELU -> bf16 — 128x128, 8 waves, 600 blocks
    gemm_bf16<1, 128, 128, 8><<<24 * 25, 512, 0, stream>>>(
        xn_b, W1t, bf1, nullptr, a1b, M1, 3072, 768, 768, 768, 24);
    // 12. fc2 split-K=2: partials (f32) — 128x64, 4 waves, 600 blocks; then merge
    gemm_bf16<4, 128, 64, 4><<<12 * 25 * 2, 256, 0, stream>>>(
        a1b, W2t, nullptr, nullptr, fc2_part, M1, 768, 1536, 3072, 3072, 12);
    fc2_merge_kernel<<<(BB * NN * (C / 4) + 255) / 256, 256, 0, stream>>>(
        fc2_part, bf2, out);
}

// Round 24
// 254.056 us; speedup vs baseline: 1.0942x; 1.0603x over previous
//
#include <hip/hip_runtime.h>
#include <hip/hip_bf16.h>
#include <math.h>

#define C     768
#define HEADS 12
#define HD    64
#define NF    8
#define SL    196
#define BB    2
#define NN    1569   // 1 + NF*SL
#define SS    1568   // NF*SL
#define HID   3072
#define CLS_CH 256
#define CLS_NC 7     // ceil(NN / CLS_CH)
#define QSCALE 0.18033688011112042f   // 0.125 * log2(e); scores live in log2 domain

typedef __attribute__((ext_vector_type(8))) short short8;
typedef __attribute__((ext_vector_type(4))) float f32x4;
typedef unsigned short u16;
typedef unsigned int u32;

__device__ inline float fast_exp2(float x) { return __builtin_amdgcn_exp2f(x); }

__device__ inline u16 f2b(float f) {
    __hip_bfloat16 h = __float2bfloat16(f);   // HW v_cvt path (RNE)
    return *reinterpret_cast<u16*>(&h);
}
__device__ inline float b2f(u16 u) {
    union { unsigned u; float f; } v; v.u = ((unsigned)u) << 16;
    return v.f;
}

__device__ inline void gload_lds16(const void* g, void* l) {
    __builtin_amdgcn_global_load_lds(
        (const __attribute__((address_space(1))) void*)g,
        (__attribute__((address_space(3))) void*)l, 16, 0, 0);
}

// ---------------- LayerNorm: f32 in -> bf16 out ----------------
__global__ void ln_kernel(const float* __restrict__ x, const float* __restrict__ g,
                          const float* __restrict__ b, u16* __restrict__ out, int rows) {
    int row = blockIdx.x;
    if (row >= rows) return;
    const float* xr = x + (size_t)row * C;
    int tid = threadIdx.x;
    float v[3];
    float sum = 0.f, sumsq = 0.f;
#pragma unroll
    for (int i = 0; i < 3; i++) {
        v[i] = xr[tid + 256 * i];
        sum += v[i]; sumsq += v[i] * v[i];
    }
    __shared__ float s1[4], s2[4];
    for (int off = 32; off; off >>= 1) {
        sum   += __shfl_xor(sum, off);
        sumsq += __shfl_xor(sumsq, off);
    }
    int wave = tid >> 6, lane = tid & 63;
    if (lane == 0) { s1[wave] = sum; s2[wave] = sumsq; }
    __syncthreads();
    sum   = s1[0] + s1[1] + s1[2] + s1[3];
    sumsq = s2[0] + s2[1] + s2[2] + s2[3];
    float mu  = sum / C;
    float var = sumsq / C - mu * mu;
    float rstd = rsqrtf(fmaxf(var, 0.f) + 1e-5f);
    u16* outr = out + (size_t)row * C;
#pragma unroll
    for (int i = 0; i < 3; i++) {
        int c = tid + 256 * i;
        outr[c] = f2b((v[i] - mu) * rstd * g[c] + b[c]);
    }
}

// ---------------- fused weight transpose+convert (all 6 weights, one launch) ----------------
__global__ void wtrans_all_kernel(
    const float* __restrict__ Wqkv, const float* __restrict__ Wq,
    const float* __restrict__ Wkv,  const float* __restrict__ Wp,
    const float* __restrict__ W1,   const float* __restrict__ W2,
    u16* Tqkv, u16* Tq, u16* Tkv, u16* Tp, u16* T1, u16* T2) {
    __shared__ float tile[64][65];
    int bid = blockIdx.x;
    const float* W; u16* Wt; int K, ldb, gx;
    if (bid < 432)       { W = Wqkv; Wt = Tqkv; K = 768;  ldb = 2304; gx = 36; }
    else if (bid < 576)  { W = Wq;   Wt = Tq;   K = 768;  ldb = 768;  gx = 12; bid -= 432; }
    else if (bid < 720)  { W = Wkv;  Wt = Tkv;  K = 768;  ldb = 1536; gx = 12; bid -= 576; }
    else if (bid < 864)  { W = Wp;   Wt = Tp;   K = 768;  ldb = 768;  gx = 12; bid -= 720; }
    else if (bid < 1440) { W = W1;   Wt = T1;   K = 768;  ldb = 3072; gx = 48; bid -= 864; }
    else                 { W = W2;   Wt = T2;   K = 3072; ldb = 768;  gx = 12; bid -= 1440; }
    int nb = (bid % gx) * 64, kb = (bid / gx) * 64;
    int tx = threadIdx.x & 63, ty = threadIdx.x >> 6;
#pragma unroll
    for (int i = 0; i < 64; i += 4)
        tile[ty + i][tx] = W[(size_t)(kb + ty + i) * ldb + nb + tx];
    __syncthreads();
#pragma unroll
    for (int i = 0; i < 64; i += 4)
        Wt[(size_t)(nb + ty + i) * K + kb + tx] = f2b(tile[tx][ty + i]);
}

// ---------------- bf16 MFMA GEMM (2-phase dbuf, XCD-swizzled 1-D grid) ----------------
// Tiled BM x BN with WAVES waves (2 rows x WAVES/2 cols); wave tile (BM/2) x (BN/(WAVES/2)).
// MODE 0: bf16 out. MODE 1: bf16 out, bias + exact GELU. MODE 2: f32 out, bias + resid.
// MODE 3: bf16 out, cols < 768 scaled by QSCALE. MODE 4: split-K f32 partials.
// MODE 6: fused k2+attn2 — acc tile (rows = 16 s x 8 f, cols = 2 heads) is never stored;
//         scores reduced in-block, softmax over f, PV from A re-read, writes y rows.
//         resid = q2 (u16), Cout = y (u16). Requires BM=BN=128, WAVES=8, N=768.
template<int MODE, int BM, int BN, int WAVES>
__global__ __launch_bounds__(WAVES * 64) void gemm_bf16(
    const u16* __restrict__ A, const u16* __restrict__ Bt,
    const float* __restrict__ bias, const float* resid, void* Cout,
    int M, int N, int K, int lda, int ldb, int gx) {
    constexpr int WCOLS = WAVES / 2;
    constexpr int WBN   = BN / WCOLS;
    constexpr int MT    = BM / 32;
    constexpr int NT    = WBN / 16;
    constexpr int ACH   = BM * 4;
    constexpr int TCH   = (BM + BN) * 4;
    constexpr int HALF  = (BM + BN) * 64;
    __shared__ char smem[2 * HALF];
    int tid = threadIdx.x, lane = tid & 63, wave = tid >> 6;
    int wr = wave / WCOLS, wc = wave % WCOLS;
    int r16 = lane & 15, kg = lane >> 4;

    int nwg = gridDim.x, orig = blockIdx.x;
    int qq = nwg >> 3, rr = nwg & 7, xcd = orig & 7, lid = orig >> 3;
    int wg = (xcd < rr ? xcd * (qq + 1) : rr * (qq + 1) + (xcd - rr) * qq) + lid;
    int bx = wg % gx, by = wg / gx;
    if constexpr (MODE == 4) {
        int mt_ = (M + BM - 1) / BM;
        int chunk = by / mt_; by -= chunk * mt_;
        A    += (size_t)chunk * K;
        Bt   += (size_t)chunk * K;
        Cout  = (void*)((float*)Cout + (size_t)chunk * ((size_t)M * N));
    }
    int row0 = by * BM, col0 = bx * BN;

    f32x4 acc[MT][NT];
#pragma unroll
    for (int mt = 0; mt < MT; mt++)
#pragma unroll
        for (int nt = 0; nt < NT; nt++) acc[mt][nt] = (f32x4){0.f, 0.f, 0.f, 0.f};

    auto stage = [&](char* dstbase, int ks) {
        int k0 = ks << 5;
#pragma unroll
        for (int it = 0; it < TCH / (WAVES * 64); it++) {
            int c = it * (WAVES * 64) + tid;
            const u16* src;
            if (c < ACH) {
                int ml = c >> 2, s = c & 3;
                int kgs = s ^ ((ml >> 1) & 3);
                int gm = row0 + ml; if (gm >= M) gm = M - 1;
                src = A + (size_t)gm * lda + k0 + kgs * 8;
            } else {
                int cc = c - ACH;
                int nl = cc >> 2, s = cc & 3;
                int kgs = s ^ ((nl >> 1) & 3);
                src = Bt + (size_t)(col0 + nl) * ldb + k0 + kgs * 8;
            }
            gload_lds16(src, dstbase + it * (WAVES * 1024) + wave * 1024);
        }
    };

    int nsteps = K >> 5;
    stage(smem, 0);
    __syncthreads();
    for (int ks = 0; ks < nsteps; ks++) {
        char* curb = smem + (ks & 1) * HALF;
        if (ks + 1 < nsteps) stage(smem + ((ks + 1) & 1) * HALF, ks + 1);
        short8 af[MT], bfr[NT];
#pragma unroll
        for (int mt = 0; mt < MT; mt++) {
            int ml = wr * (BM / 2) + mt * 16 + r16;
            af[mt] = *(const short8*)(curb + ml * 64 + ((kg ^ ((ml >> 1) & 3)) << 4));
        }
#pragma unroll
        for (int nt = 0; nt < NT; nt++) {
            int nl = wc * WBN + nt * 16 + r16;
            bfr[nt] = *(const short8*)(curb + BM * 64 + nl * 64 + ((kg ^ ((nl >> 1) & 3)) << 4));
        }
        __builtin_amdgcn_s_setprio(1);
#pragma unroll
        for (int mt = 0; mt < MT; mt++)
#pragma unroll
            for (int nt = 0; nt < NT; nt++)
                acc[mt][nt] = __builtin_amdgcn_mfma_f32_16x16x32_bf16(af[mt], bfr[nt], acc[mt][nt], 0, 0, 0);
        __builtin_amdgcn_s_setprio(0);
        __syncthreads();
    }

    if constexpr (MODE == 6) {
        // ---- fused attn2 epilogue; dbuf LDS is dead, overlay it ----
        // q2l [16][128] u16 @0 (4KB); sc2 [128][2][2] f32 @4KB (2KB); Pl [16][2][8] f32 @6KB (1KB)
        u16*   q2l = (u16*)smem;
        float* sc2 = (float*)(smem + 4096);
        float* Pl  = (float*)(smem + 6144);
        const u16* q2p = (const u16*)resid;
        {   // stage q2 slice: rows gs = by*16+s, cols bx*128..+128
            int idx = tid * 4;                         // 2048 u16 total
            int sr = idx >> 7, cc = idx & 127;
            *(uint2*)(q2l + idx) =
                *(const uint2*)(q2p + (size_t)(by * 16 + sr) * 768 + bx * 128 + cc);
        }
        __syncthreads();
        // partial scores: p(row) = sum over this thread's 2 cols; butterfly over r16
#pragma unroll
        for (int mt = 0; mt < MT; mt++) {
#pragma unroll
            for (int r2 = 0; r2 < 4; r2++) {
                int row = wr * 64 + mt * 16 + kg * 4 + r2;
                int sl = row >> 3;
                float q0v = b2f(q2l[sl * 128 + wc * 32 + r16]);
                float q1v = b2f(q2l[sl * 128 + wc * 32 + 16 + r16]);
                float p = acc[mt][0][r2] * q0v + acc[mt][1][r2] * q1v;
                p += __shfl_xor(p, 1); p += __shfl_xor(p, 2);
                p += __shfl_xor(p, 4); p += __shfl_xor(p, 8);
                if (r16 == 0)
                    sc2[(row * 2 + (wc >> 1)) * 2 + (wc & 1)] = p;
            }
        }
        __syncthreads();
        // softmax per (s_local, h_local): 32 items
        if (tid < 32) {
            int sl = tid >> 1, hl = tid & 1;
            float sc[8];
            float m = -1e30f;
#pragma unroll
            for (int ff = 0; ff < 8; ff++) {
                int row = sl * 8 + ff;
                sc[ff] = (sc2[(row * 2 + hl) * 2] + sc2[(row * 2 + hl) * 2 + 1]) * QSCALE;
                m = fmaxf(m, sc[ff]);
            }
            float sum = 0.f;
#pragma unroll
            for (int ff = 0; ff < 8; ff++) { sc[ff] = fast_exp2(sc[ff] - m); sum += sc[ff]; }
            float invp = 1.f / sum;
#pragma unroll
            for (int ff = 0; ff < 8; ff++) Pl[(sl * 2 + hl) * 8 + ff] = sc[ff] * invp;
        }
        __syncthreads();
        // PV: thread (pass,sl,c); x1 re-read from A (L2-hot), coalesced per (s,f)
        u16* yp = (u16*)Cout;
#pragma unroll
        for (int pass = 0; pass < 4; pass++) {
            int sl = pass * 4 + (tid >> 7);
            int c  = tid & 127;
            int hl = c >> 6;
            int gs = by * 16 + sl;
            float accv = 0.f;
#pragma unroll
            for (int ff = 0; ff < 8; ff++)
                accv += Pl[(sl * 2 + hl) * 8 + ff] *
                        b2f(A[(size_t)(gs * 8 + ff) * lda + bx * 128 + c]);
            int bb = gs / SS, ss2 = gs % SS;
            yp[((size_t)bb * NN + 1 + ss2) * C + bx * 128 + c] = f2b(accv);
        }
        return;
    }

#pragma unroll
    for (int mt = 0; mt < MT; mt++) {
#pragma unroll
        for (int r2 = 0; r2 < 4; r2++) {
            int gm = row0 + wr * (BM / 2) + mt * 16 + kg * 4 + r2;
            if (gm >= M) continue;
#pragma unroll
            for (int nt = 0; nt < NT; nt++) {
                int gn = col0 + wc * WBN + nt * 16 + r16;
                float v = acc[mt][nt][r2];
                if constexpr (MODE == 1) {
                    v += bias[gn];
                    v = 0.5f * v * (1.f + erff(v * 0.70710678118f));
                }
                if constexpr (MODE == 2) {
                    v += bias[gn] + resid[(size_t)gm * N + gn];
                    ((float*)Cout)[(size_t)gm * N + gn] = v;
                } else if constexpr (MODE == 4) {
                    ((float*)Cout)[(size_t)gm * N + gn] = v;
                } else {
                    if constexpr (MODE == 3) { if (gn < 768) v *= QSCALE; }
                    ((u16*)Cout)[(size_t)gm * N + gn] = f2b(v);
                }
            }
        }
    }
}

// ---------------- fc2 split-K=2 merge: out += p0+p1 + bias (float4) ----------------
__global__ void fc2_merge_kernel(const float* __restrict__ p,
                                 const float* __restrict__ bias, float* __restrict__ out) {
    int i = blockIdx.x * 256 + threadIdx.x;
    int total = BB * NN * (C / 4);
    if (i >= total) return;
    int c4 = i % (C / 4);
    size_t stride = (size_t)BB * NN * (C / 4);
    float4 bb = ((const float4*)bias)[c4];
    float4 a0 = ((const float4*)p)[i];
    float4 a1 = ((const float4*)p)[i + stride];
    float4 o  = ((float4*)out)[i];
    o.x += a0.x + a1.x + bb.x;
    o.y += a0.y + a1.y + bb.y;
    o.z += a0.z + a1.z + bb.z;
    o.w += a0.w + a1.w + bb.w;
    ((float4*)out)[i] = o;
}

// ---------------- cls attention pass 1 (q pre-scaled; log2-domain softmax) ----------------
__global__ void cls_partial_kernel(const u16* __restrict__ qkv, float* __restrict__ part) {
    int c = blockIdx.x, bh = blockIdx.y;
    int b = bh / HEADS, hh = bh % HEADS;
    int tid = threadIdx.x;
    int wave = tid >> 6, lane = tid & 63;
    __shared__ float s_q[HD];
    __shared__ float s_sc[CLS_CH];
    __shared__ float sm[4], ss[4];
    __shared__ float sacc[4][HD];
    if (tid < HD) s_q[tid] = b2f(qkv[(size_t)(b * NN) * 2304 + hh * HD + tid]);
    __syncthreads();

    int j0 = c * CLS_CH;
    int j = j0 + tid;
    float sc = -1e30f;
    if (j < NN) {
        const short8* kp = (const short8*)(qkv + ((size_t)(b * NN) + j) * 2304 + C + hh * HD);
        float acc = 0.f;
#pragma unroll
        for (int u = 0; u < 8; u++) {
            short8 kv = kp[u];
#pragma unroll
            for (int e = 0; e < 8; e++) acc += s_q[u * 8 + e] * b2f((u16)kv[e]);
        }
        sc = acc;
    }
    float m = sc;
    for (int off = 32; off; off >>= 1) m = fmaxf(m, __shfl_xor(m, off));
    if (lane == 0) sm[wave] = m;
    __syncthreads();
    m = fmaxf(fmaxf(sm[0], sm[1]), fmaxf(sm[2], sm[3]));
    float e = (j < NN) ? fast_exp2(sc - m) : 0.f;
    s_sc[tid] = e;
    float su = e;
    for (int off = 32; off; off >>= 1) su += __shfl_xor(su, off);
    if (lane == 0) ss[wave] = su;
    __syncthreads();
    float ssum = ss[0] + ss[1] + ss[2] + ss[3];

    int jj = tid >> 6, d = tid & 63;
    int jmax = NN - j0; if (jmax > CLS_CH) jmax = CLS_CH;
    const u16* vcol = qkv + ((size_t)(b * NN) + j0) * 2304 + 2 * C + hh * HD + d;
    float acc = 0.f;
    for (int t = jj; t < jmax; t += 4)
        acc += s_sc[t] * b2f(vcol[(size_t)t * 2304]);
    sacc[jj][d] = acc;
    __syncthreads();
    if (tid < HD) {
        float pv = sacc[0][tid] + sacc[1][tid] + sacc[2][tid] + sacc[3][tid];
        float* pp = part + ((size_t)bh * CLS_NC + c) * 66;
        pp[2 + tid] = pv;
        if (tid == 0) { pp[0] = m; pp[1] = ssum; }
    }
}

// ---------------- cls attention pass 2: merge chunk partials (log2 domain) ----------------
__global__ void cls_reduce_kernel(const float* __restrict__ part, u16* __restrict__ y) {
    int bh = blockIdx.x;
    int b = bh / HEADS, hh = bh % HEADS;
    int d = threadIdx.x;   // 64
    float gm = -1e30f;
#pragma unroll
    for (int c = 0; c < CLS_NC; c++)
        gm = fmaxf(gm, part[((size_t)bh * CLS_NC + c) * 66]);
    float tot = 0.f, pv = 0.f;
#pragma unroll
    for (int c = 0; c < CLS_NC; c++) {
        const float* pp = part + ((size_t)bh * CLS_NC + c) * 66;
        float w = fast_exp2(pp[0] - gm);
        tot += pp[1] * w;
        pv  += pp[2 + d] * w;
    }
    y[(size_t)(b * NN) * C + hh * HD + d] = f2b(pv / tot);
}

// ---------------- fused repack K + V ----------------
__global__ void repack_kv_kernel(const u16* __restrict__ qkv,
                                 u16* __restrict__ Kb, u16* __restrict__ Vt) {
    const int NK = 24 * NF * 208 * 8;       // 319488
    const int NV = 24 * NF * 64 * 28;       // 344064
    int t = blockIdx.x * 256 + threadIdx.x;
    if (t < NK) {
        int d8 = t & 7;
        int rest = t >> 3;
        int n = rest % 208;
        rest /= 208;
        int f = rest % NF;
        int bh = rest / NF;
        int b = bh / HEADS, h = bh % HEADS;
        short8 v = {0, 0, 0, 0, 0, 0, 0, 0};
        if (n < SL)
            v = *(const short8*)(qkv + ((size_t)(b * NN) + 1 + f * SL + n) * 2304 + C + h * HD + d8 * 8);
        *(short8*)(Kb + (((size_t)bh * NF + f) * 208 + n) * 64 + d8 * 8) = v;
    } else {
        int u = t - NK;
        if (u >= NV) return;
        int n8 = u % 28;
        int rest = u / 28;
        int d = rest % 64;
        rest /= 64;
        int f = rest % NF;
        int bh = rest / NF;
        int b = bh / HEADS, h = bh % HEADS;
        int n0 = n8 * 8;
        const u16* src = qkv + ((size_t)(b * NN) + 1 + f * SL) * 2304 + 2 * C + h * HD + d;
        short8 v;
#pragma unroll
        for (int jj = 0; jj < 8; jj++) {
            int n = n0 + jj;
            v[jj] = (n < SL) ? (short)src[(size_t)n * 2304] : (short)0;
        }
        *(short8*)(Vt + (((size_t)bh * NF + f) * 64 + d) * 224 + n0) = v;
    }
}

// ---------------- MFMA spatial attention v9 (dual-strip, shared V, shuffle-PV) ----------
__global__ void space_attn_mfma(
    const u16* __restrict__ qkv, const u16* __restrict__ Kb,
    const u16* __restrict__ Vt, u16* __restrict__ x1, u16* __restrict__ xd) {
    __shared__ u16 smem[13312];   // 26624 B: phase 1 = swizzled K_f; phase 2 = 4 x 4608B epi bufs
    int tid = threadIdx.x;
    int lane = tid & 63, wave = tid >> 6;
    int r16 = lane & 15, kg = lane >> 4;

    int n = blockIdx.x;
    int xcd = n & 7;
    int slot = n >> 3;
    int j = slot % 13;
    int gw = slot / 13;            // 0..23
    int bh = xcd * 3 + gw % 3;
    int f = gw / 3;
    int b = bh / HEADS, h = bh % HEADS;

    int sA = j * 8 + wave * 2, sB = sA + 1;
    bool actA = sA < 98, actB = sB < 98;
    int q0A = (actA ? sA : 97) * 16;
    int q0B = (actB ? sB : 97) * 16;

    const u16* qrowA = qkv + ((size_t)(b * NN) + 1 + q0A + r16) * 2304 + h * HD + kg * 8;
    const u16* qrowB = qkv + ((size_t)(b * NN) + 1 + q0B + r16) * 2304 + h * HD + kg * 8;
    short8 aqA0 = *(const short8*)(qrowA);
    short8 aqA1 = *(const short8*)(qrowA + 32);
    short8 aqB0 = *(const short8*)(qrowB);
    short8 aqB1 = *(const short8*)(qrowB + 32);

    const char* kb_g = (const char*)(Kb + ((size_t)bh * NF + f) * 208 * 64);
    for (int w = wave; w < 26; w += 4) {
        int p = w * 1024 + lane * 16;
        int row = p >> 7;
        int src = (p & ~127) | ((p & 127) ^ ((row & 7) << 4));
        gload_lds16(kb_g + src, (char*)smem + p);
    }
    __syncthreads();

    const char* ksm = (const char*)smem;
    int swz = (r16 & 7) << 4;
    bool tailz = (kg >= 1);
    const u16* vbase = Vt + ((size_t)bh * NF + f) * 64 * 224;

    f32x4 acc[13];
    u32 w0A[13], w1A[13], w0B[13], w1B[13];

#pragma unroll
    for (int t = 0; t < 13; t++) acc[t] = (f32x4){0.f, 0.f, 0.f, 0.f};
    __builtin_amdgcn_s_setprio(1);
#pragma unroll
    for (int t = 0; t < 13; t++) {
        const char* krow = ksm + (t * 16 + r16) * 128;
        short8 bk0 = *(const short8*)(krow + ((kg * 16) ^ swz));
        short8 bk1 = *(const short8*)(krow + ((64 + kg * 16) ^ swz));
        acc[t] = __builtin_amdgcn_mfma_f32_16x16x32_bf16(bk0, aqA0, acc[t], 0, 0, 0);
        acc[t] = __builtin_amdgcn_mfma_f32_16x16x32_bf16(bk1, aqA1, acc[t], 0, 0, 0);
    }
    __builtin_amdgcn_s_setprio(0);
    short8 vf[2][4];
#pragma unroll
    for (int dt = 0; dt < 4; dt++)
        vf[0][dt] = *(const short8*)(vbase + (dt * 16 + r16) * 224 + kg * 8);
    {
        float ssum = 0.f;
#pragma unroll
        for (int t = 0; t < 13; t++)
#pragma unroll
            for (int r = 0; r < 4; r++) {
                float p = (t == 12 && tailz) ? 0.f : fast_exp2(acc[t][r]);
                acc[t][r] = p;
                ssum += p;
            }
        ssum += __shfl_xor(ssum, 16);
        ssum += __shfl_xor(ssum, 32);
        float inv = 1.f / ssum;
#pragma unroll
        for (int t = 0; t < 13; t++) {
            w0A[t] = (u32)f2b(acc[t][0] * inv) | ((u32)f2b(acc[t][1] * inv) << 16);
            w1A[t] = (u32)f2b(acc[t][2] * inv) | ((u32)f2b(acc[t][3] * inv) << 16);
        }
    }

#pragma unroll
    for (int t = 0; t < 13; t++) acc[t] = (f32x4){0.f, 0.f, 0.f, 0.f};
    __builtin_amdgcn_s_setprio(1);
#pragma unroll
    for (int t = 0; t < 13; t++) {
        const char* krow = ksm + (t * 16 + r16) * 128;
        short8 bk0 = *(const short8*)(krow + ((kg * 16) ^ swz));
        short8 bk1 = *(const short8*)(krow + ((64 + kg * 16) ^ swz));
        acc[t] = __builtin_amdgcn_mfma_f32_16x16x32_bf16(bk0, aqB0, acc[t], 0, 0, 0);
        acc[t] = __builtin_amdgcn_mfma_f32_16x16x32_bf16(bk1, aqB1, acc[t], 0, 0, 0);
    }
    __builtin_amdgcn_s_setprio(0);
    {
        float ssum = 0.f;
#pragma unroll
        for (int t = 0; t < 13; t++)
#pragma unroll
            for (int r = 0; r < 4; r++) {
                float p = (t == 12 && tailz) ? 0.f : fast_exp2(acc[t][r]);
                acc[t][r] = p;
                ssum += p;
            }
        ssum += __shfl_xor(ssum, 16);
        ssum += __shfl_xor(ssum, 32);
        float inv = 1.f / ssum;
#pragma unroll
        for (int t = 0; t < 13; t++) {
            w0B[t] = (u32)f2b(acc[t][0] * inv) | ((u32)f2b(acc[t][1] * inv) << 16);
            w1B[t] = (u32)f2b(acc[t][2] * inv) | ((u32)f2b(acc[t][3] * inv) << 16);
        }
    }

    int src0 = r16 + ((kg & 1) << 5);
    int src1 = src0 + 16;
    bool thi = (kg >= 2);
    f32x4 oA[4], oB[4];
#pragma unroll
    for (int dt = 0; dt < 4; dt++) { oA[dt] = (f32x4){0.f, 0.f, 0.f, 0.f}; oB[dt] = (f32x4){0.f, 0.f, 0.f, 0.f}; }
    __builtin_amdgcn_s_setprio(1);
#pragma unroll
    for (int kc = 0; kc < 7; kc++) {
        if (kc < 6) {
#pragma unroll
            for (int dt = 0; dt < 4; dt++)
                vf[(kc + 1) & 1][dt] = *(const short8*)(vbase + (dt * 16 + r16) * 224 + (kc + 1) * 32 + kg * 8);
        }
        u32 a0, a1, b0, b1;
        if (kc == 6) {
            a0 = thi ? 0u : w0A[12]; a1 = thi ? 0u : w1A[12];
            b0 = thi ? 0u : w0B[12]; b1 = thi ? 0u : w1B[12];
        } else {
            a0 = thi ? w0A[2 * kc + 1] : w0A[2 * kc];
            a1 = thi ? w1A[2 * kc + 1] : w1A[2 * kc];
            b0 = thi ? w0B[2 * kc + 1] : w0B[2 * kc];
            b1 = thi ? w1B[2 * kc + 1] : w1B[2 * kc];
        }
        union { u32 u[4]; short8 s8; } pA, pB;
        pA.u[0] = (u32)__shfl((int)a0, src0);
        pA.u[1] = (u32)__shfl((int)a1, src0);
        pA.u[2] = (u32)__shfl((int)a0, src1);
        pA.u[3] = (u32)__shfl((int)a1, src1);
        pB.u[0] = (u32)__shfl((int)b0, src0);
        pB.u[1] = (u32)__shfl((int)b1, src0);
        pB.u[2] = (u32)__shfl((int)b0, src1);
        pB.u[3] = (u32)__shfl((int)b1, src1);
#pragma unroll
        for (int dt = 0; dt < 4; dt++) {
            oA[dt] = __builtin_amdgcn_mfma_f32_16x16x32_bf16(pA.s8, vf[kc & 1][dt], oA[dt], 0, 0, 0);
            oB[dt] = __builtin_amdgcn_mfma_f32_16x16x32_bf16(pB.s8, vf[kc & 1][dt], oB[dt], 0, 0, 0);
        }
    }
    __builtin_amdgcn_s_setprio(0);

    __syncthreads();
    u16* ebA = smem + wave * 2304;
    u16* ebB = ebA + 1152;
    int fbase = f * SL;
#pragma unroll
    for (int dt = 0; dt < 4; dt++)
#pragma unroll
        for (int r = 0; r < 4; r++) {
            ebA[(kg * 4 + r) * 72 + dt * 16 + r16] = f2b(oA[dt][r]);
            ebB[(kg * 4 + r) * 72 + dt * 16 + r16] = f2b(oB[dt][r]);
        }
    if (actA) {
        u16* x1row = x1 + (((size_t)(b * SS + q0A)) * NF + f) * C + h * HD;
        u16* xdrow = xd + ((size_t)(b * SS + q0A)) * C + h * HD;
#pragma unroll
        for (int it = 0; it < 2; it++) {
            int c = it * 64 + lane;
            int qr = c >> 3, c8 = c & 7;
            short8 v8 = *(const short8*)(&ebA[qr * 72 + c8 * 8]);
            *(short8*)(x1row + (size_t)qr * (NF * C) + c8 * 8) = v8;
            if ((unsigned)(q0A + qr - fbase) < (unsigned)SL)
                *(short8*)(xdrow + (size_t)qr * C + c8 * 8) = v8;
        }
    }
    if (actB) {
        u16* x1row = x1 + (((size_t)(b * SS + q0B)) * NF + f) * C + h * HD;
        u16* xdrow = xd + ((size_t)(b * SS + q0B)) * C + h * HD;
#pragma unroll
        for (int it = 0; it < 2; it++) {
            int c = it * 64 + lane;
            int qr = c >> 3, c8 = c & 7;
            short8 v8 = *(const short8*)(&ebB[qr * 72 + c8 * 8]);
            *(short8*)(x1row + (size_t)qr * (NF * C) + c8 * 8) = v8;
            if ((unsigned)(q0B + qr - fbase) < (unsigned)SL)
                *(short8*)(xdrow + (size_t)qr * C + c8 * 8) = v8;
        }
    }
}

extern "C" void kernel_launch(void* const* d_in, const int* in_sizes, int n_in,
                              void* d_out, int out_size, void* d_ws, size_t ws_size,
                              hipStream_t stream) {
    const float* x    = (const float*)d_in[0];
    const float* g1   = (const float*)d_in[1];
    const float* b1   = (const float*)d_in[2];
    const float* Wqkv = (const float*)d_in[3];
    const float* Wq   = (const float*)d_in[4];
    const float* Wkv  = (const float*)d_in[5];
    const float* Wp   = (const float*)d_in[6];
    const float* bp   = (const float*)d_in[7];
    const float* g2   = (const float*)d_in[8];
    const float* b2_  = (const float*)d_in[9];
    const float* W1   = (const float*)d_in[10];
    const float* bf1  = (const float*)d_in[11];
    const float* W2   = (const float*)d_in[12];
    const float* bf2  = (const float*)d_in[13];
    float* out = (float*)d_out;

    // workspace layout (u16 elements)
    u16* us     = (u16*)d_ws;
    u16* xn_b   = us;                    // M1*768    (reused as hn after LN2)
    u16* qkv_b  = xn_b   + 2409984;      // M1*2304
    u16* Wt_qkv = qkv_b  + 7229952;      // 2304*768
    u16* Wt_q   = Wt_qkv + 1769472;      // 768*768
    u16* Wt_kv  = Wt_q   + 589824;       // 768*768 (first half of Wkv)
    u16* Wt_p   = Wt_kv  + 589824;       // 768*768
    u16* W1t    = Wt_p   + 589824;       // 3072*768
    u16* W2t    = W1t    + 2359296;      // 768*3072
    u16* Kb     = W2t    + 2359296;      // 24*8*208*64
    u16* Vt     = Kb     + 2555904;      // 24*8*64*224
    u16* x1b    = Vt     + 2752512;      // B*S*F*C
    u16* xdb    = x1b    + 19267584;     // B*S*C
    u16* q2b    = xdb    + 2408448;      // B*S*C
    u16* y_b    = q2b    + 2408448;      // B*N*C
    u16* a1b    = y_b    + 2409984;      // B*N*HID
    float* cls_ws   = (float*)(a1b + 9639936);     // 24*7*66 floats
    float* fc2_part = cls_ws + 24 * 7 * 66;        // 2 * M1*768 floats

    const int M1 = BB * NN;       // 3138
    const int M2 = BB * SS;       // 3136
    const int M3 = BB * SS * NF;  // 25088

    // 0. fused weight transpose + bf16 convert (one launch)
    wtrans_all_kernel<<<2016, 256, 0, stream>>>(Wqkv, Wq, Wkv, Wp, W1, W2,
                                                Wt_qkv, Wt_q, Wt_kv, Wt_p, W1t, W2t);
    // 1. LN1 -> bf16
    ln_kernel<<<M1, 256, 0, stream>>>(x, g1, b1, xn_b, M1);
    // 2. qkv_b = xn_b @ Wqkv (bf16; q cols pre-scaled) — 128x128, 8 waves, 450 blocks
    gemm_bf16<3, 128, 128, 8><<<18 * 25, 512, 0, stream>>>(
        xn_b, Wt_qkv, nullptr, nullptr, qkv_b, M1, 2304, 768, 768, 768, 18);
    // 3. fused repack K + V
    repack_kv_kernel<<<(24 * NF * 208 * 8 + 24 * NF * 64 * 28 + 255) / 256, 256, 0, stream>>>(
        qkv_b, Kb, Vt);
    // 4. cls attention (two-pass flash-style) -> y_b row 0
    cls_partial_kernel<<<dim3(CLS_NC, BB * HEADS), 256, 0, stream>>>(qkv_b, cls_ws);
    cls_reduce_kernel<<<BB * HEADS, 64, 0, stream>>>(cls_ws, y_b);
    // 5. spatial attention -> x1b + fused diag gather -> xdb (dual-strip v9)
    space_attn_mfma<<<2496, 256, 0, stream>>>(qkv_b, Kb, Vt, x1b, xdb);
    // 6. q2 = xd @ Wq — 64x64, 4 waves, 588 blocks
    gemm_bf16<0, 64, 64, 4><<<12 * 49, 256, 0, stream>>>(
        xdb, Wt_q, nullptr, nullptr, q2b, M2, 768, 768, 768, 768, 12);
    // 7. fused k2 GEMM + temporal attention (k2 never materialized) -> y_b rows 1..S
    gemm_bf16<6, 128, 128, 8><<<6 * 196, 512, 0, stream>>>(
        x1b, Wt_kv, nullptr, (const float*)q2b, y_b, M3, 768, 768, 768, 768, 6);
    // 8. proj: out = y_b @ Wp + bp + x (f32) — 64x64, 4 waves, 600 blocks
    gemm_bf16<2, 64, 64, 4><<<12 * 50, 256, 0, stream>>>(
        y_b, Wt_p, bp, x, out, M1, 768, 768, 768, 768, 12);
    // 9. LN2 -> bf16 (reuse xn_b)
    ln_kernel<<<M1, 256, 0, stream>>>(out, g2, b2_, xn_b, M1);
    // 10. fc1 + exact GELU -> bf16 — 128x128, 8 waves, 600 blocks
    gemm_bf16<1, 128, 128, 8><<<24 * 25, 512, 0, stream>>>(
        xn_b, W1t, bf1, nullptr, a1b, M1, 3072, 768, 768, 768, 24);
    // 11. fc2 split-K=2: partials (f32) — 128x64, 4 waves, 600 blocks; then merge
    gemm_bf16<4, 128, 64, 4><<<12 * 25 * 2, 256, 0, stream>>>(
        a1b, W2t, nullptr, nullptr, fc2_part, M1, 768, 1536, 3072, 3072, 12);
    fc2_merge_kernel<<<(BB * NN * (C / 4) + 255) / 256, 256, 0, stream>>>(
        fc2_part, bf2, out);
}

// Round 25
// 251.081 us; speedup vs baseline: 1.1072x; 1.0118x over previous
//
#include <hip/hip_runtime.h>
#include <hip/hip_bf16.h>
#include <math.h>

#define C     768
#define HEADS 12
#define HD    64
#define NF    8
#define SL    196
#define BB    2
#define NN    1569   // 1 + NF*SL
#define SS    1568   // NF*SL
#define HID   3072
#define CLS_CH 256
#define CLS_NC 7     // ceil(NN / CLS_CH)
#define QSCALE 0.18033688011112042f   // 0.125 * log2(e); scores live in log2 domain

typedef __attribute__((ext_vector_type(8))) short short8;
typedef __attribute__((ext_vector_type(4))) float f32x4;
typedef unsigned short u16;
typedef unsigned int u32;

__device__ inline float fast_exp2(float x) { return __builtin_amdgcn_exp2f(x); }

__device__ inline u16 f2b(float f) {
    __hip_bfloat16 h = __float2bfloat16(f);   // HW v_cvt path (RNE)
    return *reinterpret_cast<u16*>(&h);
}
__device__ inline float b2f(u16 u) {
    union { unsigned u; float f; } v; v.u = ((unsigned)u) << 16;
    return v.f;
}

__device__ inline void gload_lds16(const void* g, void* l) {
    __builtin_amdgcn_global_load_lds(
        (const __attribute__((address_space(1))) void*)g,
        (__attribute__((address_space(3))) void*)l, 16, 0, 0);
}

// ---------------- LayerNorm: f32 in -> bf16 out ----------------
__global__ void ln_kernel(const float* __restrict__ x, const float* __restrict__ g,
                          const float* __restrict__ b, u16* __restrict__ out, int rows) {
    int row = blockIdx.x;
    if (row >= rows) return;
    const float* xr = x + (size_t)row * C;
    int tid = threadIdx.x;
    float v[3];
    float sum = 0.f, sumsq = 0.f;
#pragma unroll
    for (int i = 0; i < 3; i++) {
        v[i] = xr[tid + 256 * i];
        sum += v[i]; sumsq += v[i] * v[i];
    }
    __shared__ float s1[4], s2[4];
    for (int off = 32; off; off >>= 1) {
        sum   += __shfl_xor(sum, off);
        sumsq += __shfl_xor(sumsq, off);
    }
    int wave = tid >> 6, lane = tid & 63;
    if (lane == 0) { s1[wave] = sum; s2[wave] = sumsq; }
    __syncthreads();
    sum   = s1[0] + s1[1] + s1[2] + s1[3];
    sumsq = s2[0] + s2[1] + s2[2] + s2[3];
    float mu  = sum / C;
    float var = sumsq / C - mu * mu;
    float rstd = rsqrtf(fmaxf(var, 0.f) + 1e-5f);
    u16* outr = out + (size_t)row * C;
#pragma unroll
    for (int i = 0; i < 3; i++) {
        int c = tid + 256 * i;
        outr[c] = f2b((v[i] - mu) * rstd * g[c] + b[c]);
    }
}

// ---------------- fused weight transpose+convert (all 6 weights, one launch) ----------------
__global__ void wtrans_all_kernel(
    const float* __restrict__ Wqkv, const float* __restrict__ Wq,
    const float* __restrict__ Wkv,  const float* __restrict__ Wp,
    const float* __restrict__ W1,   const float* __restrict__ W2,
    u16* Tqkv, u16* Tq, u16* Tkv, u16* Tp, u16* T1, u16* T2) {
    __shared__ float tile[64][65];
    int bid = blockIdx.x;
    const float* W; u16* Wt; int K, ldb, gx;
    if (bid < 432)       { W = Wqkv; Wt = Tqkv; K = 768;  ldb = 2304; gx = 36; }
    else if (bid < 576)  { W = Wq;   Wt = Tq;   K = 768;  ldb = 768;  gx = 12; bid -= 432; }
    else if (bid < 720)  { W = Wkv;  Wt = Tkv;  K = 768;  ldb = 1536; gx = 12; bid -= 576; }
    else if (bid < 864)  { W = Wp;   Wt = Tp;   K = 768;  ldb = 768;  gx = 12; bid -= 720; }
    else if (bid < 1440) { W = W1;   Wt = T1;   K = 768;  ldb = 3072; gx = 48; bid -= 864; }
    else                 { W = W2;   Wt = T2;   K = 3072; ldb = 768;  gx = 12; bid -= 1440; }
    int nb = (bid % gx) * 64, kb = (bid / gx) * 64;
    int tx = threadIdx.x & 63, ty = threadIdx.x >> 6;
#pragma unroll
    for (int i = 0; i < 64; i += 4)
        tile[ty + i][tx] = W[(size_t)(kb + ty + i) * ldb + nb + tx];
    __syncthreads();
#pragma unroll
    for (int i = 0; i < 64; i += 4)
        Wt[(size_t)(nb + ty + i) * K + kb + tx] = f2b(tile[tx][ty + i]);
}

// ---------------- bf16 MFMA GEMM (2-phase dbuf, XCD-swizzled 1-D grid) ----------------
// Tiled BM x BN with WAVES waves (2 rows x WAVES/2 cols); wave tile (BM/2) x (BN/(WAVES/2)).
// MODE 0: bf16 out. MODE 1: bf16 out, bias + exact GELU. MODE 2: f32 out, bias + resid.
// MODE 3: bf16 out, cols < 768 scaled by QSCALE. MODE 4: split-K f32 partials.
// MODE 6: fused k2+attn2 — acc tile (rows = 16 s x 8 f, cols = 2 heads) is never stored;
//         q2 slice prefetched into dedicated LDS before the K-loop; scores reduced
//         in-block, softmax over f, PV from A re-read (L2-hot), writes y rows.
//         resid = q2 (u16), Cout = y (u16). Requires BM=BN=128, WAVES=8, N=768.
template<int MODE, int BM, int BN, int WAVES>
__global__ __launch_bounds__(WAVES * 64) void gemm_bf16(
    const u16* __restrict__ A, const u16* __restrict__ Bt,
    const float* __restrict__ bias, const float* resid, void* Cout,
    int M, int N, int K, int lda, int ldb, int gx) {
    constexpr int WCOLS = WAVES / 2;
    constexpr int WBN   = BN / WCOLS;
    constexpr int MT    = BM / 32;
    constexpr int NT    = WBN / 16;
    constexpr int ACH   = BM * 4;
    constexpr int TCH   = (BM + BN) * 4;
    constexpr int HALF  = (BM + BN) * 64;
    constexpr int EXTRA = (MODE == 6) ? 4096 : 0;   // dedicated q2 slice region
    __shared__ char smem[2 * HALF + EXTRA];
    int tid = threadIdx.x, lane = tid & 63, wave = tid >> 6;
    int wr = wave / WCOLS, wc = wave % WCOLS;
    int r16 = lane & 15, kg = lane >> 4;

    int nwg = gridDim.x, orig = blockIdx.x;
    int qq = nwg >> 3, rr = nwg & 7, xcd = orig & 7, lid = orig >> 3;
    int wg = (xcd < rr ? xcd * (qq + 1) : rr * (qq + 1) + (xcd - rr) * qq) + lid;
    int bx = wg % gx, by = wg / gx;
    if constexpr (MODE == 4) {
        int mt_ = (M + BM - 1) / BM;
        int chunk = by / mt_; by -= chunk * mt_;
        A    += (size_t)chunk * K;
        Bt   += (size_t)chunk * K;
        Cout  = (void*)((float*)Cout + (size_t)chunk * ((size_t)M * N));
    }
    int row0 = by * BM, col0 = bx * BN;

    f32x4 acc[MT][NT];
#pragma unroll
    for (int mt = 0; mt < MT; mt++)
#pragma unroll
        for (int nt = 0; nt < NT; nt++) acc[mt][nt] = (f32x4){0.f, 0.f, 0.f, 0.f};

    auto stage = [&](char* dstbase, int ks) {
        int k0 = ks << 5;
#pragma unroll
        for (int it = 0; it < TCH / (WAVES * 64); it++) {
            int c = it * (WAVES * 64) + tid;
            const u16* src;
            if (c < ACH) {
                int ml = c >> 2, s = c & 3;
                int kgs = s ^ ((ml >> 1) & 3);
                int gm = row0 + ml; if (gm >= M) gm = M - 1;
                src = A + (size_t)gm * lda + k0 + kgs * 8;
            } else {
                int cc = c - ACH;
                int nl = cc >> 2, s = cc & 3;
                int kgs = s ^ ((nl >> 1) & 3);
                src = Bt + (size_t)(col0 + nl) * ldb + k0 + kgs * 8;
            }
            gload_lds16(src, dstbase + it * (WAVES * 1024) + wave * 1024);
        }
    };

    if constexpr (MODE == 6) {
        // prefetch q2 slice (16 s x 128 cols) into dedicated LDS; drains under loop barriers
        if (tid < 256) {
            int sr = tid >> 4, cc = (tid * 8) & 127;
            gload_lds16((const u16*)resid + (size_t)(by * 16 + sr) * 768 + bx * 128 + cc,
                        smem + 2 * HALF + tid * 16);
        }
    }

    int nsteps = K >> 5;
    stage(smem, 0);
    __syncthreads();
    for (int ks = 0; ks < nsteps; ks++) {
        char* curb = smem + (ks & 1) * HALF;
        if (ks + 1 < nsteps) stage(smem + ((ks + 1) & 1) * HALF, ks + 1);
        short8 af[MT], bfr[NT];
#pragma unroll
        for (int mt = 0; mt < MT; mt++) {
            int ml = wr * (BM / 2) + mt * 16 + r16;
            af[mt] = *(const short8*)(curb + ml * 64 + ((kg ^ ((ml >> 1) & 3)) << 4));
        }
#pragma unroll
        for (int nt = 0; nt < NT; nt++) {
            int nl = wc * WBN + nt * 16 + r16;
            bfr[nt] = *(const short8*)(curb + BM * 64 + nl * 64 + ((kg ^ ((nl >> 1) & 3)) << 4));
        }
        __builtin_amdgcn_s_setprio(1);
#pragma unroll
        for (int mt = 0; mt < MT; mt++)
#pragma unroll
            for (int nt = 0; nt < NT; nt++)
                acc[mt][nt] = __builtin_amdgcn_mfma_f32_16x16x32_bf16(af[mt], bfr[nt], acc[mt][nt], 0, 0, 0);
        __builtin_amdgcn_s_setprio(0);
        __syncthreads();
    }

    if constexpr (MODE == 6) {
        // ---- fused attn2 epilogue; dbuf LDS is dead, overlay it ----
        // q2l: dedicated region (prefetched); sc2 [128][2][2] f32 @0; Pl [16][2][8] f32 @2048
        u16*   q2l = (u16*)(smem + 2 * HALF);
        float* sc2 = (float*)smem;
        float* Pl  = (float*)(smem + 2048);
        // partial scores: p(row) = sum over this thread's 2 cols; butterfly over r16
#pragma unroll
        for (int mt = 0; mt < MT; mt++) {
#pragma unroll
            for (int r2 = 0; r2 < 4; r2++) {
                int row = wr * 64 + mt * 16 + kg * 4 + r2;
                int sl = row >> 3;
                float q0v = b2f(q2l[sl * 128 + wc * 32 + r16]);
                float q1v = b2f(q2l[sl * 128 + wc * 32 + 16 + r16]);
                float p = acc[mt][0][r2] * q0v + acc[mt][1][r2] * q1v;
                p += __shfl_xor(p, 1); p += __shfl_xor(p, 2);
                p += __shfl_xor(p, 4); p += __shfl_xor(p, 8);
                if (r16 == 0)
                    sc2[(row * 2 + (wc >> 1)) * 2 + (wc & 1)] = p;
            }
        }
        __syncthreads();
        // softmax per (s_local, h_local): 32 items
        if (tid < 32) {
            int sl = tid >> 1, hl = tid & 1;
            float sc[8];
            float m = -1e30f;
#pragma unroll
            for (int ff = 0; ff < 8; ff++) {
                int row = sl * 8 + ff;
                sc[ff] = (sc2[(row * 2 + hl) * 2] + sc2[(row * 2 + hl) * 2 + 1]) * QSCALE;
                m = fmaxf(m, sc[ff]);
            }
            float sum = 0.f;
#pragma unroll
            for (int ff = 0; ff < 8; ff++) { sc[ff] = fast_exp2(sc[ff] - m); sum += sc[ff]; }
            float invp = 1.f / sum;
#pragma unroll
            for (int ff = 0; ff < 8; ff++) Pl[(sl * 2 + hl) * 8 + ff] = sc[ff] * invp;
        }
        __syncthreads();
        // PV: thread (pass,sl,c); x1 re-read from A (L2-hot), coalesced per (s,f)
        u16* yp = (u16*)Cout;
#pragma unroll
        for (int pass = 0; pass < 4; pass++) {
            int sl = pass * 4 + (tid >> 7);
            int c  = tid & 127;
            int hl = c >> 6;
            int gs = by * 16 + sl;
            float accv = 0.f;
#pragma unroll
            for (int ff = 0; ff < 8; ff++)
                accv += Pl[(sl * 2 + hl) * 8 + ff] *
                        b2f(A[(size_t)(gs * 8 + ff) * lda + bx * 128 + c]);
            int bb = gs / SS, ss2 = gs % SS;
            yp[((size_t)bb * NN + 1 + ss2) * C + bx * 128 + c] = f2b(accv);
        }
        return;
    }

#pragma unroll
    for (int mt = 0; mt < MT; mt++) {
#pragma unroll
        for (int r2 = 0; r2 < 4; r2++) {
            int gm = row0 + wr * (BM / 2) + mt * 16 + kg * 4 + r2;
            if (gm >= M) continue;
#pragma unroll
            for (int nt = 0; nt < NT; nt++) {
                int gn = col0 + wc * WBN + nt * 16 + r16;
                float v = acc[mt][nt][r2];
                if constexpr (MODE == 1) {
                    v += bias[gn];
                    v = 0.5f * v * (1.f + erff(v * 0.70710678118f));
                }
                if constexpr (MODE == 2) {
                    v += bias[gn] + resid[(size_t)gm * N + gn];
                    ((float*)Cout)[(size_t)gm * N + gn] = v;
                } else if constexpr (MODE == 4) {
                    ((float*)Cout)[(size_t)gm * N + gn] = v;
                } else {
                    if constexpr (MODE == 3) { if (gn < 768) v *= QSCALE; }
                    ((u16*)Cout)[(size_t)gm * N + gn] = f2b(v);
                }
            }
        }
    }
}

// ---------------- fc2 split-K=2 merge: out += p0+p1 + bias (float4) ----------------
__global__ void fc2_merge_kernel(const float* __restrict__ p,
                                 const float* __restrict__ bias, float* __restrict__ out) {
    int i = blockIdx.x * 256 + threadIdx.x;
    int total = BB * NN * (C / 4);
    if (i >= total) return;
    int c4 = i % (C / 4);
    size_t stride = (size_t)BB * NN * (C / 4);
    float4 bb = ((const float4*)bias)[c4];
    float4 a0 = ((const float4*)p)[i];
    float4 a1 = ((const float4*)p)[i + stride];
    float4 o  = ((float4*)out)[i];
    o.x += a0.x + a1.x + bb.x;
    o.y += a0.y + a1.y + bb.y;
    o.z += a0.z + a1.z + bb.z;
    o.w += a0.w + a1.w + bb.w;
    ((float4*)out)[i] = o;
}

// ---------------- cls attention pass 1 (q pre-scaled; log2-domain softmax) ----------------
__global__ void cls_partial_kernel(const u16* __restrict__ qkv, float* __restrict__ part) {
    int c = blockIdx.x, bh = blockIdx.y;
    int b = bh / HEADS, hh = bh % HEADS;
    int tid = threadIdx.x;
    int wave = tid >> 6, lane = tid & 63;
    __shared__ float s_q[HD];
    __shared__ float s_sc[CLS_CH];
    __shared__ float sm[4], ss[4];
    __shared__ float sacc[4][HD];
    if (tid < HD) s_q[tid] = b2f(qkv[(size_t)(b * NN) * 2304 + hh * HD + tid]);
    __syncthreads();

    int j0 = c * CLS_CH;
    int j = j0 + tid;
    float sc = -1e30f;
    if (j < NN) {
        const short8* kp = (const short8*)(qkv + ((size_t)(b * NN) + j) * 2304 + C + hh * HD);
        float acc = 0.f;
#pragma unroll
        for (int u = 0; u < 8; u++) {
            short8 kv = kp[u];
#pragma unroll
            for (int e = 0; e < 8; e++) acc += s_q[u * 8 + e] * b2f((u16)kv[e]);
        }
        sc = acc;
    }
    float m = sc;
    for (int off = 32; off; off >>= 1) m = fmaxf(m, __shfl_xor(m, off));
    if (lane == 0) sm[wave] = m;
    __syncthreads();
    m = fmaxf(fmaxf(sm[0], sm[1]), fmaxf(sm[2], sm[3]));
    float e = (j < NN) ? fast_exp2(sc - m) : 0.f;
    s_sc[tid] = e;
    float su = e;
    for (int off = 32; off; off >>= 1) su += __shfl_xor(su, off);
    if (lane == 0) ss[wave] = su;
    __syncthreads();
    float ssum = ss[0] + ss[1] + ss[2] + ss[3];

    int jj = tid >> 6, d = tid & 63;
    int jmax = NN - j0; if (jmax > CLS_CH) jmax = CLS_CH;
    const u16* vcol = qkv + ((size_t)(b * NN) + j0) * 2304 + 2 * C + hh * HD + d;
    float acc = 0.f;
    for (int t = jj; t < jmax; t += 4)
        acc += s_sc[t] * b2f(vcol[(size_t)t * 2304]);
    sacc[jj][d] = acc;
    __syncthreads();
    if (tid < HD) {
        float pv = sacc[0][tid] + sacc[1][tid] + sacc[2][tid] + sacc[3][tid];
        float* pp = part + ((size_t)bh * CLS_NC + c) * 66;
        pp[2 + tid] = pv;
        if (tid == 0) { pp[0] = m; pp[1] = ssum; }
    }
}

// ---------------- cls attention pass 2: merge chunk partials (log2 domain) ----------------
__global__ void cls_reduce_kernel(const float* __restrict__ part, u16* __restrict__ y) {
    int bh = blockIdx.x;
    int b = bh / HEADS, hh = bh % HEADS;
    int d = threadIdx.x;   // 64
    float gm = -1e30f;
#pragma unroll
    for (int c = 0; c < CLS_NC; c++)
        gm = fmaxf(gm, part[((size_t)bh * CLS_NC + c) * 66]);
    float tot = 0.f, pv = 0.f;
#pragma unroll
    for (int c = 0; c < CLS_NC; c++) {
        const float* pp = part + ((size_t)bh * CLS_NC + c) * 66;
        float w = fast_exp2(pp[0] - gm);
        tot += pp[1] * w;
        pv  += pp[2 + d] * w;
    }
    y[(size_t)(b * NN) * C + hh * HD + d] = f2b(pv / tot);
}

// ---------------- fused repack K + V ----------------
__global__ void repack_kv_kernel(const u16* __restrict__ qkv,
                                 u16* __restrict__ Kb, u16* __restrict__ Vt) {
    const int NK = 24 * NF * 208 * 8;       // 319488
    const int NV = 24 * NF * 64 * 28;       // 344064
    int t = blockIdx.x * 256 + threadIdx.x;
    if (t < NK) {
        int d8 = t & 7;
        int rest = t >> 3;
        int n = rest % 208;
        rest /= 208;
        int f = rest % NF;
        int bh = rest / NF;
        int b = bh / HEADS, h = bh % HEADS;
        short8 v = {0, 0, 0, 0, 0, 0, 0, 0};
        if (n < SL)
            v = *(const short8*)(qkv + ((size_t)(b * NN) + 1 + f * SL + n) * 2304 + C + h * HD + d8 * 8);
        *(short8*)(Kb + (((size_t)bh * NF + f) * 208 + n) * 64 + d8 * 8) = v;
    } else {
        int u = t - NK;
        if (u >= NV) return;
        int n8 = u % 28;
        int rest = u / 28;
        int d = rest % 64;
        rest /= 64;
        int f = rest % NF;
        int bh = rest / NF;
        int b = bh / HEADS, h = bh % HEADS;
        int n0 = n8 * 8;
        const u16* src = qkv + ((size_t)(b * NN) + 1 + f * SL) * 2304 + 2 * C + h * HD + d;
        short8 v;
#pragma unroll
        for (int jj = 0; jj < 8; jj++) {
            int n = n0 + jj;
            v[jj] = (n < SL) ? (short)src[(size_t)n * 2304] : (short)0;
        }
        *(short8*)(Vt + (((size_t)bh * NF + f) * 64 + d) * 224 + n0) = v;
    }
}

// ---------------- MFMA spatial attention v9 (dual-strip, shared V, shuffle-PV) ----------
__global__ void space_attn_mfma(
    const u16* __restrict__ qkv, const u16* __restrict__ Kb,
    const u16* __restrict__ Vt, u16* __restrict__ x1, u16* __restrict__ xd) {
    __shared__ u16 smem[13312];   // 26624 B: phase 1 = swizzled K_f; phase 2 = 4 x 4608B epi bufs
    int tid = threadIdx.x;
    int lane = tid & 63, wave = tid >> 6;
    int r16 = lane & 15, kg = lane >> 4;

    int n = blockIdx.x;
    int xcd = n & 7;
    int slot = n >> 3;
    int j = slot % 13;
    int gw = slot / 13;            // 0..23
    int bh = xcd * 3 + gw % 3;
    int f = gw / 3;
    int b = bh / HEADS, h = bh % HEADS;

    int sA = j * 8 + wave * 2, sB = sA + 1;
    bool actA = sA < 98, actB = sB < 98;
    int q0A = (actA ? sA : 97) * 16;
    int q0B = (actB ? sB : 97) * 16;

    const u16* qrowA = qkv + ((size_t)(b * NN) + 1 + q0A + r16) * 2304 + h * HD + kg * 8;
    const u16* qrowB = qkv + ((size_t)(b * NN) + 1 + q0B + r16) * 2304 + h * HD + kg * 8;
    short8 aqA0 = *(const short8*)(qrowA);
    short8 aqA1 = *(const short8*)(qrowA + 32);
    short8 aqB0 = *(const short8*)(qrowB);
    short8 aqB1 = *(const short8*)(qrowB + 32);

    const char* kb_g = (const char*)(Kb + ((size_t)bh * NF + f) * 208 * 64);
    for (int w = wave; w < 26; w += 4) {
        int p = w * 1024 + lane * 16;
        int row = p >> 7;
        int src = (p & ~127) | ((p & 127) ^ ((row & 7) << 4));
        gload_lds16(kb_g + src, (char*)smem + p);
    }
    __syncthreads();

    const char* ksm = (const char*)smem;
    int swz = (r16 & 7) << 4;
    bool tailz = (kg >= 1);
    const u16* vbase = Vt + ((size_t)bh * NF + f) * 64 * 224;

    f32x4 acc[13];
    u32 w0A[13], w1A[13], w0B[13], w1B[13];

#pragma unroll
    for (int t = 0; t < 13; t++) acc[t] = (f32x4){0.f, 0.f, 0.f, 0.f};
    __builtin_amdgcn_s_setprio(1);
#pragma unroll
    for (int t = 0; t < 13; t++) {
        const char* krow = ksm + (t * 16 + r16) * 128;
        short8 bk0 = *(const short8*)(krow + ((kg * 16) ^ swz));
        short8 bk1 = *(const short8*)(krow + ((64 + kg * 16) ^ swz));
        acc[t] = __builtin_amdgcn_mfma_f32_16x16x32_bf16(bk0, aqA0, acc[t], 0, 0, 0);
        acc[t] = __builtin_amdgcn_mfma_f32_16x16x32_bf16(bk1, aqA1, acc[t], 0, 0, 0);
    }
    __builtin_amdgcn_s_setprio(0);
    short8 vf[2][4];
#pragma unroll
    for (int dt = 0; dt < 4; dt++)
        vf[0][dt] = *(const short8*)(vbase + (dt * 16 + r16) * 224 + kg * 8);
    {
        float ssum = 0.f;
#pragma unroll
        for (int t = 0; t < 13; t++)
#pragma unroll
            for (int r = 0; r < 4; r++) {
                float p = (t == 12 && tailz) ? 0.f : fast_exp2(acc[t][r]);
                acc[t][r] = p;
                ssum += p;
            }
        ssum += __shfl_xor(ssum, 16);
        ssum += __shfl_xor(ssum, 32);
        float inv = 1.f / ssum;
#pragma unroll
        for (int t = 0; t < 13; t++) {
            w0A[t] = (u32)f2b(acc[t][0] * inv) | ((u32)f2b(acc[t][1] * inv) << 16);
            w1A[t] = (u32)f2b(acc[t][2] * inv) | ((u32)f2b(acc[t][3] * inv) << 16);
        }
    }

#pragma unroll
    for (int t = 0; t < 13; t++) acc[t] = (f32x4){0.f, 0.f, 0.f, 0.f};
    __builtin_amdgcn_s_setprio(1);
#pragma unroll
    for (int t = 0; t < 13; t++) {
        const char* krow = ksm + (t * 16 + r16) * 128;
        short8 bk0 = *(const short8*)(krow + ((kg * 16) ^ swz));
        short8 bk1 = *(const short8*)(krow + ((64 + kg * 16) ^ swz));
        acc[t] = __builtin_amdgcn_mfma_f32_16x16x32_bf16(bk0, aqB0, acc[t], 0, 0, 0);
        acc[t] = __builtin_amdgcn_mfma_f32_16x16x32_bf16(bk1, aqB1, acc[t], 0, 0, 0);
    }
    __builtin_amdgcn_s_setprio(0);
    {
        float ssum = 0.f;
#pragma unroll
        for (int t = 0; t < 13; t++)
#pragma unroll
            for (int r = 0; r < 4; r++) {
                float p = (t == 12 && tailz) ? 0.f : fast_exp2(acc[t][r]);
                acc[t][r] = p;
                ssum += p;
            }
        ssum += __shfl_xor(ssum, 16);
        ssum += __shfl_xor(ssum, 32);
        float inv = 1.f / ssum;
#pragma unroll
        for (int t = 0; t < 13; t++) {
            w0B[t] = (u32)f2b(acc[t][0] * inv) | ((u32)f2b(acc[t][1] * inv) << 16);
            w1B[t] = (u32)f2b(acc[t][2] * inv) | ((u32)f2b(acc[t][3] * inv) << 16);
        }
    }

    int src0 = r16 + ((kg & 1) << 5);
    int src1 = src0 + 16;
    bool thi = (kg >= 2);
    f32x4 oA[4], oB[4];
#pragma unroll
    for (int dt = 0; dt < 4; dt++) { oA[dt] = (f32x4){0.f, 0.f, 0.f, 0.f}; oB[dt] = (f32x4){0.f, 0.f, 0.f, 0.f}; }
    __builtin_amdgcn_s_setprio(1);
#pragma unroll
    for (int kc = 0; kc < 7; kc++) {
        if (kc < 6) {
#pragma unroll
            for (int dt = 0; dt < 4; dt++)
                vf[(kc + 1) & 1][dt] = *(const short8*)(vbase + (dt * 16 + r16) * 224 + (kc + 1) * 32 + kg * 8);
        }
        u32 a0, a1, b0, b1;
        if (kc == 6) {
            a0 = thi ? 0u : w0A[12]; a1 = thi ? 0u : w1A[12];
            b0 = thi ? 0u : w0B[12]; b1 = thi ? 0u : w1B[12];
        } else {
            a0 = thi ? w0A[2 * kc + 1] : w0A[2 * kc];
            a1 = thi ? w1A[2 * kc + 1] : w1A[2 * kc];
            b0 = thi ? w0B[2 * kc + 1] : w0B[2 * kc];
            b1 = thi ? w1B[2 * kc + 1] : w1B[2 * kc];
        }
        union { u32 u[4]; short8 s8; } pA, pB;
        pA.u[0] = (u32)__shfl((int)a0, src0);
        pA.u[1] = (u32)__shfl((int)a1, src0);
        pA.u[2] = (u32)__shfl((int)a0, src1);
        pA.u[3] = (u32)__shfl((int)a1, src1);
        pB.u[0] = (u32)__shfl((int)b0, src0);
        pB.u[1] = (u32)__shfl((int)b1, src0);
        pB.u[2] = (u32)__shfl((int)b0, src1);
        pB.u[3] = (u32)__shfl((int)b1, src1);
#pragma unroll
        for (int dt = 0; dt < 4; dt++) {
            oA[dt] = __builtin_amdgcn_mfma_f32_16x16x32_bf16(pA.s8, vf[kc & 1][dt], oA[dt], 0, 0, 0);
            oB[dt] = __builtin_amdgcn_mfma_f32_16x16x32_bf16(pB.s8, vf[kc & 1][dt], oB[dt], 0, 0, 0);
        }
    }
    __builtin_amdgcn_s_setprio(0);

    __syncthreads();
    u16* ebA = smem + wave * 2304;
    u16* ebB = ebA + 1152;
    int fbase = f * SL;
#pragma unroll
    for (int dt = 0; dt < 4; dt++)
#pragma unroll
        for (int r = 0; r < 4; r++) {
            ebA[(kg * 4 + r) * 72 + dt * 16 + r16] = f2b(oA[dt][r]);
            ebB[(kg * 4 + r) * 72 + dt * 16 + r16] = f2b(oB[dt][r]);
        }
    if (actA) {
        u16* x1row = x1 + (((size_t)(b * SS + q0A)) * NF + f) * C + h * HD;
        u16* xdrow = xd + ((size_t)(b * SS + q0A)) * C + h * HD;
#pragma unroll
        for (int it = 0; it < 2; it++) {
            int c = it * 64 + lane;
            int qr = c >> 3, c8 = c & 7;
            short8 v8 = *(const short8*)(&ebA[qr * 72 + c8 * 8]);
            *(short8*)(x1row + (size_t)qr * (NF * C) + c8 * 8) = v8;
            if ((unsigned)(q0A + qr - fbase) < (unsigned)SL)
                *(short8*)(xdrow + (size_t)qr * C + c8 * 8) = v8;
        }
    }
    if (actB) {
        u16* x1row = x1 + (((size_t)(b * SS + q0B)) * NF + f) * C + h * HD;
        u16* xdrow = xd + ((size_t)(b * SS + q0B)) * C + h * HD;
#pragma unroll
        for (int it = 0; it < 2; it++) {
            int c = it * 64 + lane;
            int qr = c >> 3, c8 = c & 7;
            short8 v8 = *(const short8*)(&ebB[qr * 72 + c8 * 8]);
            *(short8*)(x1row + (size_t)qr * (NF * C) + c8 * 8) = v8;
            if ((unsigned)(q0B + qr - fbase) < (unsigned)SL)
                *(short8*)(xdrow + (size_t)qr * C + c8 * 8) = v8;
        }
    }
}

extern "C" void kernel_launch(void* const* d_in, const int* in_sizes, int n_in,
                              void* d_out, int out_size, void* d_ws, size_t ws_size,
                              hipStream_t stream) {
    const float* x    = (const float*)d_in[0];
    const float* g1   = (const float*)d_in[1];
    const float* b1   = (const float*)d_in[2];
    const float* Wqkv = (const float*)d_in[3];
    const float* Wq   = (const float*)d_in[4];
    const float* Wkv  = (const float*)d_in[5];
    const float* Wp   = (const float*)d_in[6];
    const float* bp   = (const float*)d_in[7];
    const float* g2   = (const float*)d_in[8];
    const float* b2_  = (const float*)d_in[9];
    const float* W1   = (const float*)d_in[10];
    const float* bf1  = (const float*)d_in[11];
    const float* W2   = (const float*)d_in[12];
    const float* bf2  = (const float*)d_in[13];
    float* out = (float*)d_out;

    // workspace layout (u16 elements)
    u16* us     = (u16*)d_ws;
    u16* xn_b   = us;                    // M1*768    (reused as hn after LN2)
    u16* qkv_b  = xn_b   + 2409984;      // M1*2304
    u16* Wt_qkv = qkv_b  + 7229952;      // 2304*768
    u16* Wt_q   = Wt_qkv + 1769472;      // 768*768
    u16* Wt_kv  = Wt_q   + 589824;       // 768*768 (first half of Wkv)
    u16* Wt_p   = Wt_kv  + 589824;       // 768*768
    u16* W1t    = Wt_p   + 589824;       // 3072*768
    u16* W2t    = W1t    + 2359296;      // 768*3072
    u16* Kb     = W2t    + 2359296;      // 24*8*208*64
    u16* Vt     = Kb     + 2555904;      // 24*8*64*224
    u16* x1b    = Vt     + 2752512;      // B*S*F*C
    u16* xdb    = x1b    + 19267584;     // B*S*C
    u16* q2b    = xdb    + 2408448;      // B*S*C
    u16* y_b    = q2b    + 2408448;      // B*N*C
    u16* a1b    = y_b    + 2409984;      // B*N*HID
    float* cls_ws   = (float*)(a1b + 9639936);     // 24*7*66 floats
    float* fc2_part = cls_ws + 24 * 7 * 66;        // 2 * M1*768 floats

    const int M1 = BB * NN;       // 3138
    const int M2 = BB * SS;       // 3136
    const int M3 = BB * SS * NF;  // 25088

    // 0. fused weight transpose + bf16 convert (one launch)
    wtrans_all_kernel<<<2016, 256, 0, stream>>>(Wqkv, Wq, Wkv, Wp, W1, W2,
                                                Wt_qkv, Wt_q, Wt_kv, Wt_p, W1t, W2t);
    // 1. LN1 -> bf16
    ln_kernel<<<M1, 256, 0, stream>>>(x, g1, b1, xn_b, M1);
    // 2. qkv_b = xn_b @ Wqkv (bf16; q cols pre-scaled) — 128x128, 8 waves, 450 blocks
    gemm_bf16<3, 128, 128, 8><<<18 * 25, 512, 0, stream>>>(
        xn_b, Wt_qkv, nullptr, nullptr, qkv_b, M1, 2304, 768, 768, 768, 18);
    // 3. fused repack K + V
    repack_kv_kernel<<<(24 * NF * 208 * 8 + 24 * NF * 64 * 28 + 255) / 256, 256, 0, stream>>>(
        qkv_b, Kb, Vt);
    // 4. cls attention (two-pass flash-style) -> y_b row 0
    cls_partial_kernel<<<dim3(CLS_NC, BB * HEADS), 256, 0, stream>>>(qkv_b, cls_ws);
    cls_reduce_kernel<<<BB * HEADS, 64, 0, stream>>>(cls_ws, y_b);
    // 5. spatial attention -> x1b + fused diag gather -> xdb (dual-strip v9)
    space_attn_mfma<<<2496, 256, 0, stream>>>(qkv_b, Kb, Vt, x1b, xdb);
    // 6. q2 = xd @ Wq — 64x64, 4 waves, 588 blocks
    gemm_bf16<0, 64, 64, 4><<<12 * 49, 256, 0, stream>>>(
        xdb, Wt_q, nullptr, nullptr, q2b, M2, 768, 768, 768, 768, 12);
    // 7. fused k2 GEMM + temporal attention (k2 never materialized) -> y_b rows 1..S
    gemm_bf16<6, 128, 128, 8><<<6 * 196, 512, 0, stream>>>(
        x1b, Wt_kv, nullptr, (const float*)q2b, y_b, M3, 768, 768, 768, 768, 6);
    // 8. proj: out = y_b @ Wp + bp + x (f32) — 64x64, 4 waves, 600 blocks
    gemm_bf16<2, 64, 64, 4><<<12 * 50, 256, 0, stream>>>(
        y_b, Wt_p, bp, x, out, M1, 768, 768, 768, 768, 12);
    // 9. LN2 -> bf16 (reuse xn_b)
    ln_kernel<<<M1, 256, 0, stream>>>(out, g2, b2_, xn_b, M1);
    // 10. fc1 + exact GELU -> bf16 — 128x128, 8 waves, 600 blocks
    gemm_bf16<1, 128, 128, 8><<<24 * 25, 512, 0, stream>>>(
        xn_b, W1t, bf1, nullptr, a1b, M1, 3072, 768, 768, 768, 24);
    // 11. fc2 split-K=2: partials (f32) — 128x128, 8 waves, 300 blocks; then merge
    gemm_bf16<4, 128, 128, 8><<<6 * 25 * 2, 512, 0, stream>>>(
        a1b, W2t, nullptr, nullptr, fc2_part, M1, 768, 1536, 3072, 3072, 6);
    fc2_merge_kernel<<<(BB * NN * (C / 4) + 255) / 256, 256, 0, stream>>>(
        fc2_part, bf2, out);
}